// Round 7
// baseline (2094.033 us; speedup 1.0000x reference)
//
#include <hip/hip_runtime.h>
#include <hip/hip_bf16.h>
#include <stdint.h>

#define DEPTH 4
#define DIM   1024
#define DH    4096
#define NH    8
#define DQ    128
#define VOC   32000
#define BATCH 2
#define SEQ   1024
#define ROWS  (BATCH*SEQ)   // 2048

#define PQKV  ((long long)ROWS*DIM)
#define PQKV3 ((long long)ROWS*3*DIM)
#define PROT  ((long long)BATCH*NH*SEQ*2*DQ)
#define PVT   ((long long)BATCH*NH*DQ*SEQ)
#define PS    ((long long)BATCH*NH*SEQ*SEQ)
#define PMID  ((long long)ROWS*DH)
#define PY    ((long long)ROWS*DIM)

typedef __hip_bfloat16 bf16;
using f32x4  = __attribute__((ext_vector_type(4))) float;
using bf16x8 = __attribute__((ext_vector_type(8))) __bf16;

__device__ __forceinline__ void wpair(bf16* p, long long off, long long plane, float v) {
  bf16 hi = __float2bfloat16(v);
  p[off] = hi;
  p[off + plane] = __float2bfloat16(v - __bfloat162float(hi));
}

__device__ __forceinline__ void gload_lds16(const void* g, void* l) {
  __builtin_amdgcn_global_load_lds(
      (const __attribute__((address_space(1))) void*)g,
      (__attribute__((address_space(3))) void*)(uintptr_t)l,
      16, 0, 0);
}

#define VMW(n) asm volatile("s_waitcnt vmcnt(" #n ")" ::: "memory")

// ===========================================================================
// 256x256 8-phase counted-vmcnt GEMM (T2+T3+T4+T5), batch-1, B^T input.
// C = sum over passes p: A(+aoff_p) * B(+boff_p)^T ; K_eff = NPASS*K.
// grid: (M/256, N/256, ksplit). 512 thr (8 waves 2Mx4N), 128 KiB LDS dbuf.
// Staging: 8 units/tile (8KB = 64 rows x 64 cols, linear LDS, chunk-XOR
// swizzled global src), issued 2/phase one tile ahead, order
// [A0,A2,B0,B1,B2,B3,A1,A3]; waits: vmcnt(4) after phase1, vmcnt(2) after
// phase3 (never drain in steady state). Phase q computes m-frags {2q,2q+1}
// x 4 n-frags x 2 kslices = 16 MFMA; B-frags (8) register-resident per tile.
// EPI 0: C = acc+bias (z==0)   3: C += acc (+bias z==0), atomic if ksplit>1
// ===========================================================================
template<int EPI, int NPASS>
__global__ __launch_bounds__(512, 2)
void gemm256(const bf16* __restrict__ A, long long aoff1, long long aoff2, int lda,
             const bf16* __restrict__ B, long long boff1, long long boff2, int ldb,
             float* __restrict__ C, int ldc,
             const float* __restrict__ bias,
             int M, int N, int K, int ksplit)
{
  __shared__ char sh[131072];
  const int tid  = threadIdx.x;
  const int lane = tid & 63;
  const int wid  = tid >> 6;
  const int wr   = wid >> 2;          // 0..1 -> rows wr*128..+128
  const int wc   = wid & 3;           // 0..3 -> cols wc*64..+64
  const int z    = blockIdx.z;
  const int tm   = blockIdx.x * 256;
  const int tn   = blockIdx.y * 256;
  const int nt   = (K * NPASS / 64) / ksplit;
  const int g0   = z * nt;

  // stage unit u of global K-tile g into LDS buffer b
  auto stage = [&](int g, int b, int u) {
    int kt = g * 64;
    long long ao = 0, bo = 0;
    if (NPASS >= 2 && kt >= K) {
      if (NPASS >= 3 && kt >= 2*K) { ao = aoff2; bo = boff2; kt -= 2*K; }
      else                         { ao = aoff1; bo = boff1; kt -= K; }
    }
    int mat, s;
    switch (u) { case 0: mat=0; s=0; break;  case 1: mat=0; s=2; break;
                 case 2: mat=1; s=0; break;  case 3: mat=1; s=1; break;
                 case 4: mat=1; s=2; break;  case 5: mat=1; s=3; break;
                 case 6: mat=0; s=1; break;  default: mat=0; s=3; break; }
    int row = s*64 + (tid >> 3);
    int gc  = (tid & 7) ^ (row & 7);       // inverse-swizzled global chunk
    const bf16* src = mat
        ? (B + bo + (long long)(tn + row) * ldb + kt + gc*8)
        : (A + ao + (long long)(tm + row) * lda + kt + gc*8);
    gload_lds16(src, sh + b*65536 + mat*32768 + s*8192 + wid*1024);
  };
  auto rdA = [&](int b, int mf, int ks) -> int4 {
    int m = wr*128 + mf*16 + (lane & 15);
    int c = ks*4 + (lane >> 4);
    return *(const int4*)(sh + b*65536 + m*128 + ((c ^ (m & 7)) << 4));
  };
  auto rdB = [&](int b, int g, int ks) -> int4 {
    int n = wc*64 + g*16 + (lane & 15);
    int c = ks*4 + (lane >> 4);
    return *(const int4*)(sh + b*65536 + 32768 + n*128 + ((c ^ (n & 7)) << 4));
  };

  f32x4 acc[8][4] = {};
  int4  bfr[2][4];

  // prologue: stage tile g0 fully into buf 0; first 6 units must land.
#pragma unroll
  for (int u = 0; u < 8; ++u) stage(g0, 0, u);
  VMW(2);
  __builtin_amdgcn_s_barrier();
  __builtin_amdgcn_sched_barrier(0);

  for (int j = 0; j < nt; ++j) {
    const int  b    = j & 1;
    const bool more = (j + 1 < nt);
    const int  gn1  = g0 + j + 1;
#pragma unroll
    for (int q = 0; q < 4; ++q) {
      const int mf0 = 2*q, mf1 = 2*q + 1;
      int4 a00 = rdA(b, mf0, 0), a01 = rdA(b, mf0, 1);
      int4 a10 = rdA(b, mf1, 0), a11 = rdA(b, mf1, 1);
      if (q == 0) {
#pragma unroll
        for (int ks = 0; ks < 2; ++ks)
#pragma unroll
          for (int g = 0; g < 4; ++g) bfr[ks][g] = rdB(b, g, ks);
      }
      if (more) { stage(gn1, b^1, 2*q); stage(gn1, b^1, 2*q + 1); }
      __builtin_amdgcn_s_barrier();
      asm volatile("s_waitcnt lgkmcnt(0)" ::: "memory");
      __builtin_amdgcn_sched_barrier(0);
      __builtin_amdgcn_s_setprio(1);
#pragma unroll
      for (int g = 0; g < 4; ++g)
        acc[mf0][g] = __builtin_amdgcn_mfma_f32_16x16x32_bf16(
            __builtin_bit_cast(bf16x8, a00), __builtin_bit_cast(bf16x8, bfr[0][g]),
            acc[mf0][g], 0, 0, 0);
#pragma unroll
      for (int g = 0; g < 4; ++g)
        acc[mf0][g] = __builtin_amdgcn_mfma_f32_16x16x32_bf16(
            __builtin_bit_cast(bf16x8, a01), __builtin_bit_cast(bf16x8, bfr[1][g]),
            acc[mf0][g], 0, 0, 0);
#pragma unroll
      for (int g = 0; g < 4; ++g)
        acc[mf1][g] = __builtin_amdgcn_mfma_f32_16x16x32_bf16(
            __builtin_bit_cast(bf16x8, a10), __builtin_bit_cast(bf16x8, bfr[0][g]),
            acc[mf1][g], 0, 0, 0);
#pragma unroll
      for (int g = 0; g < 4; ++g)
        acc[mf1][g] = __builtin_amdgcn_mfma_f32_16x16x32_bf16(
            __builtin_bit_cast(bf16x8, a11), __builtin_bit_cast(bf16x8, bfr[1][g]),
            acc[mf1][g], 0, 0, 0);
      __builtin_amdgcn_s_setprio(0);
      if (q == 1) { if (more) VMW(4); else VMW(0); }   // tile j's A1,A3 ready
      if (q == 3) { if (more) VMW(2); }                // tile j+1's first-6 ready
      __builtin_amdgcn_s_barrier();
      __builtin_amdgcn_sched_barrier(0);
    }
  }

  const int col = lane & 15;
  const int rb  = (lane >> 4) << 2;
#pragma unroll
  for (int mf = 0; mf < 8; ++mf)
#pragma unroll
    for (int g = 0; g < 4; ++g) {
      long long gn = tn + wc*64 + g*16 + col;
      float bv = (z == 0 && bias) ? bias[gn] : 0.f;
#pragma unroll
      for (int r = 0; r < 4; ++r) {
        long long gm = tm + wr*128 + mf*16 + rb + r;
        long long off = gm * (long long)ldc + gn;
        float v = acc[mf][g][r] + bv;
        if (EPI == 0) C[off] = v;
        else { if (ksplit > 1) atomicAdd(&C[off], v); else C[off] += v; }
      }
    }
}

// ---------------------------------------------------------------------------
// 128x128 2-phase batched GEMM (retained for batched/causal/pair epilogues)
// ---------------------------------------------------------------------------
#define BM 128
#define BN 128
#define BKK 64
#define PL 16384

template<int EPI, int SA, int SB>
__global__ __launch_bounds__(256, (SA || SB) ? 2 : 4)
void gemm_bt(const bf16* __restrict__ A, long long sA, long long pA, int lda,
             const bf16* __restrict__ B, long long sB, long long pB, int ldb, int bmod,
             void* __restrict__ Cv, long long sC, long long pC, int ldc,
             const float* __restrict__ bias, int hmod,
             int M, int N, int K, int ksplit, int causal)
{
  __shared__ int4 sbuf[1024 * (2 + SA + SB)];
  char* Asb = (char*)sbuf;
  char* Bsb = Asb + PL * (1 + SA);

  const int tid  = threadIdx.x;
  const int lane = tid & 63;
  const int wave = tid >> 6;
  const int wr   = wave >> 1;
  const int wc   = wave & 1;
  const int z    = blockIdx.z;
  const int zb   = z / ksplit;
  const int ks   = z - zb * ksplit;
  const int Kc   = K / ksplit;
  const int k0   = ks * Kc;
  const int tm   = blockIdx.x * BM;
  const int tn   = blockIdx.y * BN;

  if (causal == 1 && tn >= tm + BM) return;
  int kend = k0 + Kc;
  if (causal == 2) {
    kend = min(kend, tm + BM);
    if (kend <= k0) return;
  }

  const bf16* Ab = A + (long long)zb * sA;
  const bf16* Bb = B + (long long)(zb % bmod) * sB;

  f32x4 acc[4][4] = {};

  for (int kt = k0; kt < kend; kt += BKK) {
#pragma unroll
    for (int j = 0; j < 4; ++j) {
      int slot0 = j*256 + wave*64;
      int i = slot0 + lane;
      int row = i >> 3;
      int gc  = (i & 7) ^ (row & 7);
      long long ga = (long long)(tm + row) * lda + kt + gc*8;
      long long gb = (long long)(tn + row) * ldb + kt + gc*8;
      gload_lds16(Ab + ga, Asb + slot0*16);
      if (SA) gload_lds16(Ab + pA + ga, Asb + PL + slot0*16);
      gload_lds16(Bb + gb, Bsb + slot0*16);
      if (SB) gload_lds16(Bb + pB + gb, Bsb + PL + slot0*16);
    }
    __syncthreads();
#pragma unroll
    for (int kh = 0; kh < 2; ++kh) {
      const int cb = kh*4 + (lane >> 4);
      int4 avh[4], bvh[4], avl[4], bvl[4];
#pragma unroll
      for (int mi = 0; mi < 4; ++mi) {
        int m = wr*64 + mi*16 + (lane & 15);
        int off = m*128 + ((cb ^ (m & 7)) << 4);
        avh[mi] = *(const int4*)(Asb + off);
        if (SA) avl[mi] = *(const int4*)(Asb + PL + off);
      }
#pragma unroll
      for (int nj = 0; nj < 4; ++nj) {
        int n = wc*64 + nj*16 + (lane & 15);
        int off = n*128 + ((cb ^ (n & 7)) << 4);
        bvh[nj] = *(const int4*)(Bsb + off);
        if (SB) bvl[nj] = *(const int4*)(Bsb + PL + off);
      }
#pragma unroll
      for (int mi = 0; mi < 4; ++mi)
#pragma unroll
        for (int nj = 0; nj < 4; ++nj)
          acc[mi][nj] = __builtin_amdgcn_mfma_f32_16x16x32_bf16(
              __builtin_bit_cast(bf16x8, avh[mi]),
              __builtin_bit_cast(bf16x8, bvh[nj]), acc[mi][nj], 0, 0, 0);
      if (SA)
#pragma unroll
        for (int mi = 0; mi < 4; ++mi)
#pragma unroll
          for (int nj = 0; nj < 4; ++nj)
            acc[mi][nj] = __builtin_amdgcn_mfma_f32_16x16x32_bf16(
                __builtin_bit_cast(bf16x8, avl[mi]),
                __builtin_bit_cast(bf16x8, bvh[nj]), acc[mi][nj], 0, 0, 0);
      if (SB)
#pragma unroll
        for (int mi = 0; mi < 4; ++mi)
#pragma unroll
          for (int nj = 0; nj < 4; ++nj)
            acc[mi][nj] = __builtin_amdgcn_mfma_f32_16x16x32_bf16(
                __builtin_bit_cast(bf16x8, avh[mi]),
                __builtin_bit_cast(bf16x8, bvl[nj]), acc[mi][nj], 0, 0, 0);
    }
    __syncthreads();
  }

  const float* dtab = (EPI == 7) ? bias + (zb % hmod) * (SEQ + 1) : nullptr;
  const int col = lane & 15;
  const int rb  = (lane >> 4) << 2;
  float* Cf = (float*)Cv + (long long)zb * sC;
  bf16*  Ch = (bf16*) Cv + (long long)zb * sC;

#pragma unroll
  for (int mi = 0; mi < 4; ++mi)
#pragma unroll
    for (int nj = 0; nj < 4; ++nj) {
      long long gn = tn + wc*64 + nj*16 + col;
      float bv_ = (EPI != 7 && bias && ks == 0) ? bias[gn] : 0.f;
#pragma unroll
      for (int r = 0; r < 4; ++r) {
        long long gm = tm + wr*64 + mi*16 + rb + r;
        float v = acc[mi][nj][r] + bv_;
        long long off = gm * (long long)ldc + gn;
        if (EPI == 0)      Cf[off] = v;
        else if (EPI == 3) { if (ksplit > 1) atomicAdd(&Cf[off], v); else Cf[off] += v; }
        else if (EPI == 5) wpair(Ch, off, pC, v);
        else if (EPI == 6) wpair(Ch, off, pC, v / (1.f + __expf(-v)));
        else {
          long long dlt = gm - gn;
          float dcy = (dlt >= 0) ? dtab[dlt] : 0.f;
          Ch[off] = __float2bfloat16(acc[mi][nj][r] * dcy);
        }
      }
    }
}

// ---------------------------------------------------------------------------
__global__ void castw_kernel(const float* __restrict__ wq, const float* __restrict__ wk,
                             const float* __restrict__ wv, const float* __restrict__ wo,
                             const float* __restrict__ f1, const float* __restrict__ f2,
                             bf16* __restrict__ Wqkv, bf16* __restrict__ Wol,
                             bf16* __restrict__ Wf1, bf16* __restrict__ Wf2) {
  const long long S1 = (long long)DIM*DIM;
  const long long WP = 3*S1;
  long long i = (long long)blockIdx.x * blockDim.x + threadIdx.x;
  if (i < 3*S1) {
    const float* src = (i < S1) ? wq : (i < 2*S1) ? wk : wv;
    float v = src[i & (S1-1)];
    bf16 h = __float2bfloat16(v);
    Wqkv[i] = h;
    Wqkv[i + WP] = __float2bfloat16(v - __bfloat162float(h));
  } else if (i < 4*S1) {
    long long j = i - 3*S1;
    float v = wo[j];
    bf16 h = __float2bfloat16(v);
    Wol[j] = h;
    Wol[j + S1] = __float2bfloat16(v - __bfloat162float(h));
  } else if (i < 8*S1) {
    long long j = i - 4*S1;
    float v = f1[j];
    bf16 h = __float2bfloat16(v);
    Wf1[j] = h;
    Wf1[j + 4*S1] = __float2bfloat16(v - __bfloat162float(h));
  } else if (i < 12*S1) {
    long long j = i - 8*S1;
    Wf2[j] = __float2bfloat16(f2[j]);
  }
}

#define MISC_LC   (NH*DQ*DQ)
#define MISC_B3   (MISC_LC + 3*DIM)
#define MISC_DC   (MISC_B3 + NH*(SEQ+1))
#define MISC_ZR   (MISC_DC + (BATCH*NH*SEQ*DQ)/4)
__global__ void misc_kernel(const float* __restrict__ lcr, const float* __restrict__ lci,
                            bf16* __restrict__ lc,
                            const float* __restrict__ bq, const float* __restrict__ bk,
                            const float* __restrict__ bv, float* __restrict__ qkvbi,
                            const float* __restrict__ amp, float* __restrict__ dtab,
                            float4* __restrict__ retz) {
  long long i = (long long)blockIdx.x * blockDim.x + threadIdx.x;
  if (i < MISC_LC) {
    int d = i & 127, e = (i >> 7) & 127, h = i >> 14;
    float vr = lcr[((long long)h*DQ + d)*DQ + e];
    float vi = lci[((long long)h*DQ + d)*DQ + e];
    long long dst = ((long long)h*DQ + e)*(2*DQ) + d;
    lc[dst]      = __float2bfloat16(vr);
    lc[dst + DQ] = __float2bfloat16(-vi);
  } else if (i < MISC_B3) {
    int j = (int)(i - MISC_LC);
    qkvbi[j] = (j < DIM) ? bq[j] : (j < 2*DIM) ? bk[j - DIM] : bv[j - 2*DIM];
  } else if (i < MISC_DC) {
    int j = (int)(i - MISC_B3);
    int h = j / (SEQ+1), n = j % (SEQ+1);
    float a = 1.f / (1.f + __expf(-amp[h]));
    dtab[j] = powf(a, (float)n);
  } else if (i < MISC_ZR) {
    retz[i - MISC_DC] = float4{0.f, 0.f, 0.f, 0.f};
  }
}

#define TIN_X4 ((long long)ROWS*VOC/4)
#define TIN_W4 (TIN_X4 + (long long)DIM*VOC/4)
#define TIN_H4 (TIN_W4 + (long long)ROWS*DIM/4)
__global__ void tinprep_kernel(const float* __restrict__ x, bf16* __restrict__ xb,
                               const float* __restrict__ tw, bf16* __restrict__ twb,
                               float4* __restrict__ hz) {
  long long i = (long long)blockIdx.x * blockDim.x + threadIdx.x;
  const float* src; bf16* dst; long long j;
  if (i < TIN_X4)      { src = x;  dst = xb;  j = i; }
  else if (i < TIN_W4) { src = tw; dst = twb; j = i - TIN_X4; }
  else if (i < TIN_H4) { hz[i - TIN_W4] = float4{0.f,0.f,0.f,0.f}; return; }
  else return;
  float4 v = ((const float4*)src)[j];
  ushort4 o{__builtin_bit_cast(unsigned short, __float2bfloat16(v.x)),
            __builtin_bit_cast(unsigned short, __float2bfloat16(v.y)),
            __builtin_bit_cast(unsigned short, __float2bfloat16(v.z)),
            __builtin_bit_cast(unsigned short, __float2bfloat16(v.w))};
  ((ushort4*)dst)[j] = o;
}

#define TAIL_H (PQKV)
#define TAIL_W (TAIL_H + (long long)VOC*DIM/4)
__global__ void tailprep_kernel(const float* __restrict__ h, bf16* __restrict__ hb,
                                const float* __restrict__ tw, bf16* __restrict__ twb) {
  long long i = (long long)blockIdx.x * blockDim.x + threadIdx.x;
  if (i < TAIL_H) {
    float v = h[i];
    bf16 hi = __float2bfloat16(v);
    hb[i] = hi;
    hb[i + PQKV] = __float2bfloat16(v - __bfloat162float(hi));
  } else if (i < TAIL_W) {
    long long j = i - TAIL_H;
    float4 v = ((const float4*)tw)[j];
    ushort4 o{__builtin_bit_cast(unsigned short, __float2bfloat16(v.x)),
              __builtin_bit_cast(unsigned short, __float2bfloat16(v.y)),
              __builtin_bit_cast(unsigned short, __float2bfloat16(v.z)),
              __builtin_bit_cast(unsigned short, __float2bfloat16(v.w))};
    ((ushort4*)twb)[j] = o;
  }
}

__global__ void ln_kernel(const float* __restrict__ in, bf16* __restrict__ out) {
  const int row = blockIdx.x;
  const int tid = threadIdx.x;
  const float4 v = ((const float4*)(in + (size_t)row*DIM))[tid];
  float s  = v.x + v.y + v.z + v.w;
  float s2 = v.x*v.x + v.y*v.y + v.z*v.z + v.w*v.w;
#pragma unroll
  for (int o = 32; o > 0; o >>= 1) { s += __shfl_xor(s, o); s2 += __shfl_xor(s2, o); }
  __shared__ float red[8];
  const int wv = tid >> 6;
  if ((tid & 63) == 0) { red[wv] = s; red[4 + wv] = s2; }
  __syncthreads();
  s  = red[0] + red[1] + red[2] + red[3];
  s2 = red[4] + red[5] + red[6] + red[7];
  const float mean = s * (1.f / DIM);
  const float var  = s2 * (1.f / DIM) - mean * mean;
  const float inv  = rsqrtf(var + 1e-5f);
  long long base = (long long)row*DIM + tid*4;
  wpair(out, base + 0, PQKV, (v.x - mean) * inv);
  wpair(out, base + 1, PQKV, (v.y - mean) * inv);
  wpair(out, base + 2, PQKV, (v.z - mean) * inv);
  wpair(out, base + 3, PQKV, (v.w - mean) * inv);
}

__global__ void rotate_kernel(const bf16* __restrict__ qkv,
                              const float* __restrict__ pre, const float* __restrict__ pim,
                              const float* __restrict__ dtab,
                              bf16* __restrict__ qrot, bf16* __restrict__ krot,
                              bf16* __restrict__ qwb) {
  const int d = threadIdx.x, l = blockIdx.x, h = blockIdx.y, b = blockIdx.z;
  const float tr = pre[h*DQ + d], ti = pim[h*DQ + d];
  const float theta = atan2f(ti, tr);
  const long long rowb = (long long)(b*SEQ + l)*(3*DIM) + h*DQ + d;
  const float qv = __bfloat162float(qkv[rowb]) + __bfloat162float(qkv[rowb + PQKV3]);
  const float kv = __bfloat162float(qkv[rowb + DIM]) + __bfloat162float(qkv[rowb + DIM + PQKV3]);
  float sn, cs;
  sincosf(theta * (float)l, &sn, &cs);
  const long long dst = ((long long)(b*NH + h)*SEQ + l)*(2*DQ) + d;
  qrot[dst]      = __float2bfloat16(qv * cs);
  qrot[dst + DQ] = __float2bfloat16(qv * sn);
  krot[dst]      = __float2bfloat16(kv * cs);
  krot[dst + DQ] = __float2bfloat16(kv * sn);
  float sn2, cs2;
  sincosf(theta * (float)(l + 1), &sn2, &cs2);
  const float ad = dtab[h*(SEQ+1) + l + 1];
  qwb[dst]      = __float2bfloat16(qv * ad * cs2);
  qwb[dst + DQ] = __float2bfloat16(qv * ad * sn2);
}

__global__ void vt_kernel(const bf16* __restrict__ qkv, bf16* __restrict__ vt) {
  __shared__ float tile[64][65];
  const int t  = threadIdx.x;
  const int c  = t & 63, r4 = t >> 6;
  const int m0 = blockIdx.x * 64;
  const int d0 = blockIdx.y * 64;
  const int h  = blockIdx.z & (NH - 1);
  const int b  = blockIdx.z >> 3;
#pragma unroll
  for (int rr = 0; rr < 64; rr += 4) {
    const int m = m0 + rr + r4;
    const long long src = (long long)(b*SEQ + m)*(3*DIM) + 2*DIM + h*DQ + d0 + c;
    tile[rr + r4][c] = __bfloat162float(qkv[src]) + __bfloat162float(qkv[src + PQKV3]);
  }
  __syncthreads();
#pragma unroll
  for (int rr = 0; rr < 64; rr += 4) {
    const int d = rr + r4;
    vt[((long long)(b*NH + h)*DQ + d0 + d)*SEQ + m0 + c] = __float2bfloat16(tile[c][d]);
  }
}

__global__ void siluret_kernel(const float* __restrict__ ret, bf16* __restrict__ y) {
  const int d = threadIdx.x, l = blockIdx.x, h = blockIdx.y, b = blockIdx.z;
  float r = ret[((long long)(b*NH + h)*SEQ + l)*DQ + d];
  float s = r / (1.f + __expf(-r));
  wpair(y, ((long long)(b*SEQ + l)*NH + h)*DQ + d, PY, s);
}

// ---------------------------------------------------------------------------
extern "C" void kernel_launch(void* const* d_in, const int* in_sizes, int n_in,
                              void* d_out, int out_size, void* d_ws, size_t ws_size,
                              hipStream_t stream) {
  const float* x      = (const float*)d_in[0];
  const float* tin_w  = (const float*)d_in[1];
  const float* tin_b  = (const float*)d_in[2];
  const float* tout_w = (const float*)d_in[3];
  const float* tout_b = (const float*)d_in[4];
  const float* wq_w   = (const float*)d_in[5];
  const float* wq_b   = (const float*)d_in[6];
  const float* wk_w   = (const float*)d_in[7];
  const float* wk_b   = (const float*)d_in[8];
  const float* wv_w   = (const float*)d_in[9];
  const float* wv_b   = (const float*)d_in[10];
  const float* wo_w   = (const float*)d_in[11];
  const float* wo_b   = (const float*)d_in[12];
  const float* f1_w   = (const float*)d_in[13];
  const float* f1_b   = (const float*)d_in[14];
  const float* f2_w   = (const float*)d_in[15];
  const float* f2_b   = (const float*)d_in[16];
  const float* phz_re = (const float*)d_in[17];
  const float* phz_im = (const float*)d_in[18];
  const float* amp    = (const float*)d_in[19];
  const float* lc_re  = (const float*)d_in[20];
  const float* lc_im  = (const float*)d_in[21];
  (void)in_sizes; (void)n_in; (void)out_size; (void)ws_size;

  char* w = (char*)d_ws;
  auto alloc = [&](size_t bytes) {
    char* p = w; w += (bytes + 255) & ~(size_t)255; return p;
  };
  auto palloc = [&](long long elems) {
    return (bf16*)alloc((size_t)elems * 2 * 2);
  };

  const long long WP = 3LL*DIM*DIM;
  float* h     = (float*)alloc((size_t)ROWS*DIM*4);
  float* ret   = (float*)alloc((size_t)BATCH*NH*SEQ*DQ*4);
  float* qkvbi = (float*)alloc((size_t)3*DIM*4);
  float* dtab  = (float*)alloc((size_t)NH*(SEQ+1)*4);
  bf16*  hb    = palloc(PQKV);
  bf16*  Wqkv  = palloc(WP);
  bf16*  Wol   = palloc((long long)DIM*DIM);
  bf16*  Wf1l  = palloc((long long)DH*DIM);
  bf16*  Wf2l  = (bf16*)alloc((size_t)DIM*DH*2);
  bf16*  qkvb  = palloc(PQKV3);
  bf16*  lcc   = (bf16*)alloc((size_t)NH*DQ*2*DQ*2);
  bf16*  Wbig  = (bf16*)alloc((size_t)DIM*VOC*2);
  bf16*  qrot  = (bf16*)alloc((size_t)PROT*2);
  bf16*  krot  = (bf16*)alloc((size_t)PROT*2);
  bf16*  qwb   = (bf16*)alloc((size_t)PROT*2);
  bf16*  vtb   = (bf16*)alloc((size_t)PVT*2);
  bf16*  Sb    = (bf16*)alloc((size_t)PS*2);
  bf16*  mid   = palloc(PMID);
  bf16*  xb = (bf16*)d_out;
  bf16*  yb = qkvb;

  auto gemm = [&](int epi, int sa, int sb, const bf16* A, long long sA, long long pA, int lda,
                  const bf16* B, long long sB, long long pB, int ldb, int bmod,
                  void* C, long long sC, long long pC, int ldc,
                  const float* bias, int hmod, int M, int N, int K, int batch,
                  int ksplit, int causal) {
    dim3 g(M / BM, N / BN, batch * ksplit), blk(256);
    if (epi == 3 && !sa && !sb)      gemm_bt<3,0,0><<<g, blk, 0, stream>>>(A,sA,pA,lda,B,sB,pB,ldb,bmod,C,sC,pC,ldc,bias,hmod,M,N,K,ksplit,causal);
    else if (epi == 7)               gemm_bt<7,0,0><<<g, blk, 0, stream>>>(A,sA,pA,lda,B,sB,pB,ldb,bmod,C,sC,pC,ldc,bias,hmod,M,N,K,ksplit,causal);
    else if (epi == 3 && sa && !sb)  gemm_bt<3,1,0><<<g, blk, 0, stream>>>(A,sA,pA,lda,B,sB,pB,ldb,bmod,C,sC,pC,ldc,bias,hmod,M,N,K,ksplit,causal);
    else if (epi == 3)               gemm_bt<3,1,1><<<g, blk, 0, stream>>>(A,sA,pA,lda,B,sB,pB,ldb,bmod,C,sC,pC,ldc,bias,hmod,M,N,K,ksplit,causal);
    else if (epi == 5)               gemm_bt<5,1,1><<<g, blk, 0, stream>>>(A,sA,pA,lda,B,sB,pB,ldb,bmod,C,sC,pC,ldc,bias,hmod,M,N,K,ksplit,causal);
    else if (epi == 6)               gemm_bt<6,1,1><<<g, blk, 0, stream>>>(A,sA,pA,lda,B,sB,pB,ldb,bmod,C,sC,pC,ldc,bias,hmod,M,N,K,ksplit,causal);
  };
  const int BIG = 1 << 30;

  // ---- input projection: gemm256 split-K x10 (atomic into zeroed h) ----
  tinprep_kernel<<<dim3((unsigned)((TIN_H4 + 255) / 256)), dim3(256), 0, stream>>>(
      x, xb, tin_w, Wbig, (float4*)h);
  gemm256<3,1><<<dim3(ROWS/256, DIM/256, 10), dim3(512), 0, stream>>>(
      xb, 0, 0, VOC, Wbig, 0, 0, VOC, h, DIM, tin_b, ROWS, DIM, VOC, 10);

  for (int i = 0; i < DEPTH; ++i) {
    castw_kernel<<<dim3((unsigned)((12LL*DIM*DIM + 255) / 256)), dim3(256), 0, stream>>>(
        wq_w + (size_t)i*DIM*DIM, wk_w + (size_t)i*DIM*DIM, wv_w + (size_t)i*DIM*DIM,
        wo_w + (size_t)i*DIM*DIM, f1_w + (size_t)i*DH*DIM, f2_w + (size_t)i*DIM*DH,
        Wqkv, Wol, Wf1l, Wf2l);
    misc_kernel<<<dim3((unsigned)((MISC_ZR + 255) / 256)), dim3(256), 0, stream>>>(
        lc_re + (size_t)i*NH*DQ*DQ, lc_im + (size_t)i*NH*DQ*DQ, lcc,
        wq_b + i*DIM, wk_b + i*DIM, wv_b + i*DIM, qkvbi,
        amp + i*NH, dtab, (float4*)ret);

    // retention
    ln_kernel<<<ROWS, 256, 0, stream>>>(h, hb);
    gemm(5, 1, 1, hb, 0, PQKV, DIM, Wqkv, 0, WP, DIM, BIG,
         qkvb, 0, PQKV3, 3*DIM, qkvbi, 1, ROWS, 3*DIM, DIM, 1, 1, 0);
    rotate_kernel<<<dim3(SEQ, NH, BATCH), DQ, 0, stream>>>(
        qkvb, phz_re + i*NH*DQ, phz_im + i*NH*DQ, dtab, qrot, krot, qwb);
    vt_kernel<<<dim3(SEQ/64, DQ/64, BATCH*NH), 256, 0, stream>>>(qkvb, vtb);
    gemm(7, 0, 0, qrot, (long long)SEQ*2*DQ, 0, 2*DQ,
         krot, (long long)SEQ*2*DQ, 0, 2*DQ, BIG,
         Sb, (long long)SEQ*SEQ, 0, SEQ, dtab, NH, SEQ, SEQ, 2*DQ, BATCH*NH, 1, 1);
    gemm(3, 0, 0, Sb, (long long)SEQ*SEQ, 0, SEQ,
         vtb, (long long)DQ*SEQ, 0, SEQ, BIG,
         ret, (long long)SEQ*DQ, 0, DQ, nullptr, 1, SEQ, DQ, SEQ, BATCH*NH, 4, 2);
    gemm(3, 0, 0, qwb, (long long)SEQ*2*DQ, 0, 2*DQ,
         lcc, (long long)DQ*2*DQ, 0, 2*DQ, NH,
         ret, (long long)SEQ*DQ, 0, DQ, nullptr, 1, SEQ, DQ, 2*DQ, BATCH*NH, 2, 0);
    siluret_kernel<<<dim3(SEQ, NH, BATCH), DQ, 0, stream>>>(ret, yb);
    gemm(3, 1, 1, yb, 0, PY, DIM, Wol, 0, (long long)DIM*DIM, DIM, BIG,
         h, 0, 0, DIM, wo_b + i*DIM, 1, ROWS, DIM, DIM, 1, 2, 0);

    // FFN
    ln_kernel<<<ROWS, 256, 0, stream>>>(h, hb);
    gemm(6, 1, 1, hb, 0, PQKV, DIM, Wf1l, 0, (long long)DH*DIM, DIM, BIG,
         mid, 0, PMID, DH, f1_b + i*DH, 1, ROWS, DH, DIM, 1, 1, 0);
    // f2: gemm256 2-pass (Ah*Bh + Al*Bh), split-K x8, atomic into h
    gemm256<3,2><<<dim3(ROWS/256, DIM/256, 8), dim3(512), 0, stream>>>(
        mid, PMID, 0, DH, Wf2l, 0, 0, DH, h, DIM, f2_b + i*DIM, ROWS, DIM, DH, 8);
  }

  // ---- output projection: gemm256 2-pass (A=hb pair, B=tout_w hi) ----
  tailprep_kernel<<<dim3((unsigned)((TAIL_W + 255) / 256)), dim3(256), 0, stream>>>(
      h, hb, tout_w, Wbig);
  gemm256<0,2><<<dim3(ROWS/256, VOC/256, 1), dim3(512), 0, stream>>>(
      hb, PQKV, 0, DIM, Wbig, 0, 0, DIM, (float*)d_out, VOC, tout_b,
      ROWS, VOC, DIM, 1);
}

// Round 8
// 2077.469 us; speedup vs baseline: 1.0080x; 1.0080x over previous
//
#include <hip/hip_runtime.h>
#include <hip/hip_bf16.h>
#include <stdint.h>

#define DEPTH 4
#define DIM   1024
#define DH    4096
#define NH    8
#define DQ    128
#define VOC   32000
#define BATCH 2
#define SEQ   1024
#define ROWS  (BATCH*SEQ)   // 2048

#define PQKV  ((long long)ROWS*DIM)
#define PQKV3 ((long long)ROWS*3*DIM)
#define PROT  ((long long)BATCH*NH*SEQ*2*DQ)
#define PVT   ((long long)BATCH*NH*DQ*SEQ)
#define PS    ((long long)BATCH*NH*SEQ*SEQ)
#define PMID  ((long long)ROWS*DH)
#define PY    ((long long)ROWS*DIM)

typedef __hip_bfloat16 bf16;
using f32x4  = __attribute__((ext_vector_type(4))) float;
using bf16x8 = __attribute__((ext_vector_type(8))) __bf16;

__device__ __forceinline__ void wpair(bf16* p, long long off, long long plane, float v) {
  bf16 hi = __float2bfloat16(v);
  p[off] = hi;
  p[off + plane] = __float2bfloat16(v - __bfloat162float(hi));
}

__device__ __forceinline__ void gload_lds16(const void* g, void* l) {
  __builtin_amdgcn_global_load_lds(
      (const __attribute__((address_space(1))) void*)g,
      (__attribute__((address_space(3))) void*)(uintptr_t)l,
      16, 0, 0);
}

#define VMW(n) asm volatile("s_waitcnt vmcnt(" #n ")" ::: "memory")

// XCD-aware bijective remap (m204): dispatch id f -> work id f'.
// Same-XCD blocks (f%8) get a contiguous chunk of work ids, decoded m-fastest,
// so blocks sharing a B n-panel co-reside on one XCD's L2. Needs nwg%8==0.
__device__ __forceinline__ int2 xcd_remap(int gx, int gy) {
  int f  = blockIdx.x + gx * blockIdx.y;
  int nwg = gx * gy;
  int fp = (f & 7) * (nwg >> 3) + (f >> 3);
  return int2{fp % gx, fp / gx};
}

// ===========================================================================
// 256x256 8-phase counted-vmcnt GEMM (T1+T2+T3+T4+T5), batch-1, B^T input.
// C = sum over passes p: A(+aoff_p) * B(+boff_p)^T ; K_eff = NPASS*K.
// grid: (M/256, N/256, ksplit). 512 thr (8 waves 2Mx4N), 128 KiB LDS dbuf.
// EPI 0: C = acc+bias (z==0)   3: C += acc (+bias z==0), atomic if ksplit>1
// ===========================================================================
template<int EPI, int NPASS>
__global__ __launch_bounds__(512, 2)
void gemm256(const bf16* __restrict__ A, long long aoff1, long long aoff2, int lda,
             const bf16* __restrict__ B, long long boff1, long long boff2, int ldb,
             float* __restrict__ C, int ldc,
             const float* __restrict__ bias,
             int M, int N, int K, int ksplit)
{
  __shared__ char sh[131072];
  const int tid  = threadIdx.x;
  const int lane = tid & 63;
  const int wid  = tid >> 6;
  const int wr   = wid >> 2;
  const int wc   = wid & 3;
  const int z    = blockIdx.z;
  const int2 xy  = xcd_remap(gridDim.x, gridDim.y);
  const int tm   = xy.x * 256;
  const int tn   = xy.y * 256;
  const int nt   = (K * NPASS / 64) / ksplit;
  const int g0   = z * nt;

  auto stage = [&](int g, int b, int u) {
    int kt = g * 64;
    long long ao = 0, bo = 0;
    if (NPASS >= 2 && kt >= K) {
      if (NPASS >= 3 && kt >= 2*K) { ao = aoff2; bo = boff2; kt -= 2*K; }
      else                         { ao = aoff1; bo = boff1; kt -= K; }
    }
    int mat, s;
    switch (u) { case 0: mat=0; s=0; break;  case 1: mat=0; s=2; break;
                 case 2: mat=1; s=0; break;  case 3: mat=1; s=1; break;
                 case 4: mat=1; s=2; break;  case 5: mat=1; s=3; break;
                 case 6: mat=0; s=1; break;  default: mat=0; s=3; break; }
    int row = s*64 + (tid >> 3);
    int gc  = (tid & 7) ^ (row & 7);
    const bf16* src = mat
        ? (B + bo + (long long)(tn + row) * ldb + kt + gc*8)
        : (A + ao + (long long)(tm + row) * lda + kt + gc*8);
    gload_lds16(src, sh + b*65536 + mat*32768 + s*8192 + wid*1024);
  };
  auto rdA = [&](int b, int mf, int ks) -> int4 {
    int m = wr*128 + mf*16 + (lane & 15);
    int c = ks*4 + (lane >> 4);
    return *(const int4*)(sh + b*65536 + m*128 + ((c ^ (m & 7)) << 4));
  };
  auto rdB = [&](int b, int g, int ks) -> int4 {
    int n = wc*64 + g*16 + (lane & 15);
    int c = ks*4 + (lane >> 4);
    return *(const int4*)(sh + b*65536 + 32768 + n*128 + ((c ^ (n & 7)) << 4));
  };

  f32x4 acc[8][4] = {};
  int4  bfr[2][4];

#pragma unroll
  for (int u = 0; u < 8; ++u) stage(g0, 0, u);
  VMW(2);
  __builtin_amdgcn_s_barrier();
  __builtin_amdgcn_sched_barrier(0);

  for (int j = 0; j < nt; ++j) {
    const int  b    = j & 1;
    const bool more = (j + 1 < nt);
    const int  gn1  = g0 + j + 1;
#pragma unroll
    for (int q = 0; q < 4; ++q) {
      const int mf0 = 2*q, mf1 = 2*q + 1;
      int4 a00 = rdA(b, mf0, 0), a01 = rdA(b, mf0, 1);
      int4 a10 = rdA(b, mf1, 0), a11 = rdA(b, mf1, 1);
      if (q == 0) {
#pragma unroll
        for (int ks = 0; ks < 2; ++ks)
#pragma unroll
          for (int g = 0; g < 4; ++g) bfr[ks][g] = rdB(b, g, ks);
      }
      if (more) { stage(gn1, b^1, 2*q); stage(gn1, b^1, 2*q + 1); }
      __builtin_amdgcn_s_barrier();
      asm volatile("s_waitcnt lgkmcnt(0)" ::: "memory");
      __builtin_amdgcn_sched_barrier(0);
      __builtin_amdgcn_s_setprio(1);
#pragma unroll
      for (int g = 0; g < 4; ++g)
        acc[mf0][g] = __builtin_amdgcn_mfma_f32_16x16x32_bf16(
            __builtin_bit_cast(bf16x8, a00), __builtin_bit_cast(bf16x8, bfr[0][g]),
            acc[mf0][g], 0, 0, 0);
#pragma unroll
      for (int g = 0; g < 4; ++g)
        acc[mf0][g] = __builtin_amdgcn_mfma_f32_16x16x32_bf16(
            __builtin_bit_cast(bf16x8, a01), __builtin_bit_cast(bf16x8, bfr[1][g]),
            acc[mf0][g], 0, 0, 0);
#pragma unroll
      for (int g = 0; g < 4; ++g)
        acc[mf1][g] = __builtin_amdgcn_mfma_f32_16x16x32_bf16(
            __builtin_bit_cast(bf16x8, a10), __builtin_bit_cast(bf16x8, bfr[0][g]),
            acc[mf1][g], 0, 0, 0);
#pragma unroll
      for (int g = 0; g < 4; ++g)
        acc[mf1][g] = __builtin_amdgcn_mfma_f32_16x16x32_bf16(
            __builtin_bit_cast(bf16x8, a11), __builtin_bit_cast(bf16x8, bfr[1][g]),
            acc[mf1][g], 0, 0, 0);
      __builtin_amdgcn_s_setprio(0);
      if (q == 1) { if (more) VMW(4); else VMW(0); }
      if (q == 3) { if (more) VMW(2); }
      __builtin_amdgcn_s_barrier();
      __builtin_amdgcn_sched_barrier(0);
    }
  }

  const int col = lane & 15;
  const int rb  = (lane >> 4) << 2;
#pragma unroll
  for (int mf = 0; mf < 8; ++mf)
#pragma unroll
    for (int g = 0; g < 4; ++g) {
      long long gn = tn + wc*64 + g*16 + col;
      float bv = (z == 0 && bias) ? bias[gn] : 0.f;
#pragma unroll
      for (int r = 0; r < 4; ++r) {
        long long gm = tm + wr*128 + mf*16 + rb + r;
        long long off = gm * (long long)ldc + gn;
        float v = acc[mf][g][r] + bv;
        if (EPI == 0) C[off] = v;
        else { if (ksplit > 1) atomicAdd(&C[off], v); else C[off] += v; }
      }
    }
}

// ---------------------------------------------------------------------------
// 128x128 2-phase batched GEMM (batched/causal/pair epilogues) + XCD swizzle
// ---------------------------------------------------------------------------
#define BM 128
#define BN 128
#define BKK 64
#define PL 16384

template<int EPI, int SA, int SB>
__global__ __launch_bounds__(256, (SA || SB) ? 2 : 4)
void gemm_bt(const bf16* __restrict__ A, long long sA, long long pA, int lda,
             const bf16* __restrict__ B, long long sB, long long pB, int ldb, int bmod,
             void* __restrict__ Cv, long long sC, long long pC, int ldc,
             const float* __restrict__ bias, int hmod,
             int M, int N, int K, int ksplit, int causal)
{
  __shared__ int4 sbuf[1024 * (2 + SA + SB)];
  char* Asb = (char*)sbuf;
  char* Bsb = Asb + PL * (1 + SA);

  const int tid  = threadIdx.x;
  const int lane = tid & 63;
  const int wave = tid >> 6;
  const int wr   = wave >> 1;
  const int wc   = wave & 1;
  const int z    = blockIdx.z;
  const int zb   = z / ksplit;
  const int ks   = z - zb * ksplit;
  const int Kc   = K / ksplit;
  const int k0   = ks * Kc;
  const int2 xy  = xcd_remap(gridDim.x, gridDim.y);
  const int tm   = xy.x * BM;
  const int tn   = xy.y * BN;

  if (causal == 1 && tn >= tm + BM) return;
  int kend = k0 + Kc;
  if (causal == 2) {
    kend = min(kend, tm + BM);
    if (kend <= k0) return;
  }

  const bf16* Ab = A + (long long)zb * sA;
  const bf16* Bb = B + (long long)(zb % bmod) * sB;

  f32x4 acc[4][4] = {};

  for (int kt = k0; kt < kend; kt += BKK) {
#pragma unroll
    for (int j = 0; j < 4; ++j) {
      int slot0 = j*256 + wave*64;
      int i = slot0 + lane;
      int row = i >> 3;
      int gc  = (i & 7) ^ (row & 7);
      long long ga = (long long)(tm + row) * lda + kt + gc*8;
      long long gb = (long long)(tn + row) * ldb + kt + gc*8;
      gload_lds16(Ab + ga, Asb + slot0*16);
      if (SA) gload_lds16(Ab + pA + ga, Asb + PL + slot0*16);
      gload_lds16(Bb + gb, Bsb + slot0*16);
      if (SB) gload_lds16(Bb + pB + gb, Bsb + PL + slot0*16);
    }
    __syncthreads();
#pragma unroll
    for (int kh = 0; kh < 2; ++kh) {
      const int cb = kh*4 + (lane >> 4);
      int4 avh[4], bvh[4], avl[4], bvl[4];
#pragma unroll
      for (int mi = 0; mi < 4; ++mi) {
        int m = wr*64 + mi*16 + (lane & 15);
        int off = m*128 + ((cb ^ (m & 7)) << 4);
        avh[mi] = *(const int4*)(Asb + off);
        if (SA) avl[mi] = *(const int4*)(Asb + PL + off);
      }
#pragma unroll
      for (int nj = 0; nj < 4; ++nj) {
        int n = wc*64 + nj*16 + (lane & 15);
        int off = n*128 + ((cb ^ (n & 7)) << 4);
        bvh[nj] = *(const int4*)(Bsb + off);
        if (SB) bvl[nj] = *(const int4*)(Bsb + PL + off);
      }
#pragma unroll
      for (int mi = 0; mi < 4; ++mi)
#pragma unroll
        for (int nj = 0; nj < 4; ++nj)
          acc[mi][nj] = __builtin_amdgcn_mfma_f32_16x16x32_bf16(
              __builtin_bit_cast(bf16x8, avh[mi]),
              __builtin_bit_cast(bf16x8, bvh[nj]), acc[mi][nj], 0, 0, 0);
      if (SA)
#pragma unroll
        for (int mi = 0; mi < 4; ++mi)
#pragma unroll
          for (int nj = 0; nj < 4; ++nj)
            acc[mi][nj] = __builtin_amdgcn_mfma_f32_16x16x32_bf16(
                __builtin_bit_cast(bf16x8, avl[mi]),
                __builtin_bit_cast(bf16x8, bvh[nj]), acc[mi][nj], 0, 0, 0);
      if (SB)
#pragma unroll
        for (int mi = 0; mi < 4; ++mi)
#pragma unroll
          for (int nj = 0; nj < 4; ++nj)
            acc[mi][nj] = __builtin_amdgcn_mfma_f32_16x16x32_bf16(
                __builtin_bit_cast(bf16x8, avh[mi]),
                __builtin_bit_cast(bf16x8, bvl[nj]), acc[mi][nj], 0, 0, 0);
    }
    __syncthreads();
  }

  const float* dtab = (EPI == 7) ? bias + (zb % hmod) * (SEQ + 1) : nullptr;
  const int col = lane & 15;
  const int rb  = (lane >> 4) << 2;
  float* Cf = (float*)Cv + (long long)zb * sC;
  bf16*  Ch = (bf16*) Cv + (long long)zb * sC;

#pragma unroll
  for (int mi = 0; mi < 4; ++mi)
#pragma unroll
    for (int nj = 0; nj < 4; ++nj) {
      long long gn = tn + wc*64 + nj*16 + col;
      float bv_ = (EPI != 7 && bias && ks == 0) ? bias[gn] : 0.f;
#pragma unroll
      for (int r = 0; r < 4; ++r) {
        long long gm = tm + wr*64 + mi*16 + rb + r;
        float v = acc[mi][nj][r] + bv_;
        long long off = gm * (long long)ldc + gn;
        if (EPI == 0)      Cf[off] = v;
        else if (EPI == 3) { if (ksplit > 1) atomicAdd(&Cf[off], v); else Cf[off] += v; }
        else if (EPI == 5) wpair(Ch, off, pC, v);
        else if (EPI == 6) wpair(Ch, off, pC, v / (1.f + __expf(-v)));
        else {
          long long dlt = gm - gn;
          float dcy = (dlt >= 0) ? dtab[dlt] : 0.f;
          Ch[off] = __float2bfloat16(acc[mi][nj][r] * dcy);
        }
      }
    }
}

// ---------------------------------------------------------------------------
__global__ void castw_kernel(const float* __restrict__ wq, const float* __restrict__ wk,
                             const float* __restrict__ wv, const float* __restrict__ wo,
                             const float* __restrict__ f1, const float* __restrict__ f2,
                             bf16* __restrict__ Wqkv, bf16* __restrict__ Wol,
                             bf16* __restrict__ Wf1, bf16* __restrict__ Wf2) {
  const long long S1 = (long long)DIM*DIM;
  const long long WP = 3*S1;
  long long i = (long long)blockIdx.x * blockDim.x + threadIdx.x;
  if (i < 3*S1) {
    const float* src = (i < S1) ? wq : (i < 2*S1) ? wk : wv;
    float v = src[i & (S1-1)];
    bf16 h = __float2bfloat16(v);
    Wqkv[i] = h;
    Wqkv[i + WP] = __float2bfloat16(v - __bfloat162float(h));
  } else if (i < 4*S1) {
    long long j = i - 3*S1;
    float v = wo[j];
    bf16 h = __float2bfloat16(v);
    Wol[j] = h;
    Wol[j + S1] = __float2bfloat16(v - __bfloat162float(h));
  } else if (i < 8*S1) {
    long long j = i - 4*S1;
    float v = f1[j];
    bf16 h = __float2bfloat16(v);
    Wf1[j] = h;
    Wf1[j + 4*S1] = __float2bfloat16(v - __bfloat162float(h));
  } else if (i < 12*S1) {
    long long j = i - 8*S1;
    Wf2[j] = __float2bfloat16(f2[j]);
  }
}

#define MISC_LC   (NH*DQ*DQ)
#define MISC_B3   (MISC_LC + 3*DIM)
#define MISC_DC   (MISC_B3 + NH*(SEQ+1))
#define MISC_ZR   (MISC_DC + (BATCH*NH*SEQ*DQ)/4)
__global__ void misc_kernel(const float* __restrict__ lcr, const float* __restrict__ lci,
                            bf16* __restrict__ lc,
                            const float* __restrict__ bq, const float* __restrict__ bk,
                            const float* __restrict__ bv, float* __restrict__ qkvbi,
                            const float* __restrict__ amp, float* __restrict__ dtab,
                            float4* __restrict__ retz) {
  long long i = (long long)blockIdx.x * blockDim.x + threadIdx.x;
  if (i < MISC_LC) {
    int d = i & 127, e = (i >> 7) & 127, h = i >> 14;
    float vr = lcr[((long long)h*DQ + d)*DQ + e];
    float vi = lci[((long long)h*DQ + d)*DQ + e];
    long long dst = ((long long)h*DQ + e)*(2*DQ) + d;
    lc[dst]      = __float2bfloat16(vr);
    lc[dst + DQ] = __float2bfloat16(-vi);
  } else if (i < MISC_B3) {
    int j = (int)(i - MISC_LC);
    qkvbi[j] = (j < DIM) ? bq[j] : (j < 2*DIM) ? bk[j - DIM] : bv[j - 2*DIM];
  } else if (i < MISC_DC) {
    int j = (int)(i - MISC_B3);
    int h = j / (SEQ+1), n = j % (SEQ+1);
    float a = 1.f / (1.f + __expf(-amp[h]));
    dtab[j] = powf(a, (float)n);
  } else if (i < MISC_ZR) {
    retz[i - MISC_DC] = float4{0.f, 0.f, 0.f, 0.f};
  }
}

#define TIN_X4 ((long long)ROWS*VOC/4)
#define TIN_W4 (TIN_X4 + (long long)DIM*VOC/4)
#define TIN_H4 (TIN_W4 + (long long)ROWS*DIM/4)
__global__ void tinprep_kernel(const float* __restrict__ x, bf16* __restrict__ xb,
                               const float* __restrict__ tw, bf16* __restrict__ twb,
                               float4* __restrict__ hz) {
  long long i = (long long)blockIdx.x * blockDim.x + threadIdx.x;
  const float* src; bf16* dst; long long j;
  if (i < TIN_X4)      { src = x;  dst = xb;  j = i; }
  else if (i < TIN_W4) { src = tw; dst = twb; j = i - TIN_X4; }
  else if (i < TIN_H4) { hz[i - TIN_W4] = float4{0.f,0.f,0.f,0.f}; return; }
  else return;
  float4 v = ((const float4*)src)[j];
  ushort4 o{__builtin_bit_cast(unsigned short, __float2bfloat16(v.x)),
            __builtin_bit_cast(unsigned short, __float2bfloat16(v.y)),
            __builtin_bit_cast(unsigned short, __float2bfloat16(v.z)),
            __builtin_bit_cast(unsigned short, __float2bfloat16(v.w))};
  ((ushort4*)dst)[j] = o;
}

#define TAIL_H (PQKV)
#define TAIL_W (TAIL_H + (long long)VOC*DIM/4)
__global__ void tailprep_kernel(const float* __restrict__ h, bf16* __restrict__ hb,
                                const float* __restrict__ tw, bf16* __restrict__ twb) {
  long long i = (long long)blockIdx.x * blockDim.x + threadIdx.x;
  if (i < TAIL_H) {
    float v = h[i];
    bf16 hi = __float2bfloat16(v);
    hb[i] = hi;
    hb[i + PQKV] = __float2bfloat16(v - __bfloat162float(hi));
  } else if (i < TAIL_W) {
    long long j = i - TAIL_H;
    float4 v = ((const float4*)tw)[j];
    ushort4 o{__builtin_bit_cast(unsigned short, __float2bfloat16(v.x)),
              __builtin_bit_cast(unsigned short, __float2bfloat16(v.y)),
              __builtin_bit_cast(unsigned short, __float2bfloat16(v.z)),
              __builtin_bit_cast(unsigned short, __float2bfloat16(v.w))};
    ((ushort4*)twb)[j] = o;
  }
}

__global__ void ln_kernel(const float* __restrict__ in, bf16* __restrict__ out) {
  const int row = blockIdx.x;
  const int tid = threadIdx.x;
  const float4 v = ((const float4*)(in + (size_t)row*DIM))[tid];
  float s  = v.x + v.y + v.z + v.w;
  float s2 = v.x*v.x + v.y*v.y + v.z*v.z + v.w*v.w;
#pragma unroll
  for (int o = 32; o > 0; o >>= 1) { s += __shfl_xor(s, o); s2 += __shfl_xor(s2, o); }
  __shared__ float red[8];
  const int wv = tid >> 6;
  if ((tid & 63) == 0) { red[wv] = s; red[4 + wv] = s2; }
  __syncthreads();
  s  = red[0] + red[1] + red[2] + red[3];
  s2 = red[4] + red[5] + red[6] + red[7];
  const float mean = s * (1.f / DIM);
  const float var  = s2 * (1.f / DIM) - mean * mean;
  const float inv  = rsqrtf(var + 1e-5f);
  long long base = (long long)row*DIM + tid*4;
  wpair(out, base + 0, PQKV, (v.x - mean) * inv);
  wpair(out, base + 1, PQKV, (v.y - mean) * inv);
  wpair(out, base + 2, PQKV, (v.z - mean) * inv);
  wpair(out, base + 3, PQKV, (v.w - mean) * inv);
}

__global__ void rotate_kernel(const bf16* __restrict__ qkv,
                              const float* __restrict__ pre, const float* __restrict__ pim,
                              const float* __restrict__ dtab,
                              bf16* __restrict__ qrot, bf16* __restrict__ krot,
                              bf16* __restrict__ qwb) {
  const int d = threadIdx.x, l = blockIdx.x, h = blockIdx.y, b = blockIdx.z;
  const float tr = pre[h*DQ + d], ti = pim[h*DQ + d];
  const float theta = atan2f(ti, tr);
  const long long rowb = (long long)(b*SEQ + l)*(3*DIM) + h*DQ + d;
  const float qv = __bfloat162float(qkv[rowb]) + __bfloat162float(qkv[rowb + PQKV3]);
  const float kv = __bfloat162float(qkv[rowb + DIM]) + __bfloat162float(qkv[rowb + DIM + PQKV3]);
  float sn, cs;
  sincosf(theta * (float)l, &sn, &cs);
  const long long dst = ((long long)(b*NH + h)*SEQ + l)*(2*DQ) + d;
  qrot[dst]      = __float2bfloat16(qv * cs);
  qrot[dst + DQ] = __float2bfloat16(qv * sn);
  krot[dst]      = __float2bfloat16(kv * cs);
  krot[dst + DQ] = __float2bfloat16(kv * sn);
  float sn2, cs2;
  sincosf(theta * (float)(l + 1), &sn2, &cs2);
  const float ad = dtab[h*(SEQ+1) + l + 1];
  qwb[dst]      = __float2bfloat16(qv * ad * cs2);
  qwb[dst + DQ] = __float2bfloat16(qv * ad * sn2);
}

__global__ void vt_kernel(const bf16* __restrict__ qkv, bf16* __restrict__ vt) {
  __shared__ float tile[64][65];
  const int t  = threadIdx.x;
  const int c  = t & 63, r4 = t >> 6;
  const int m0 = blockIdx.x * 64;
  const int d0 = blockIdx.y * 64;
  const int h  = blockIdx.z & (NH - 1);
  const int b  = blockIdx.z >> 3;
#pragma unroll
  for (int rr = 0; rr < 64; rr += 4) {
    const int m = m0 + rr + r4;
    const long long src = (long long)(b*SEQ + m)*(3*DIM) + 2*DIM + h*DQ + d0 + c;
    tile[rr + r4][c] = __bfloat162float(qkv[src]) + __bfloat162float(qkv[src + PQKV3]);
  }
  __syncthreads();
#pragma unroll
  for (int rr = 0; rr < 64; rr += 4) {
    const int d = rr + r4;
    vt[((long long)(b*NH + h)*DQ + d0 + d)*SEQ + m0 + c] = __float2bfloat16(tile[c][d]);
  }
}

__global__ void siluret_kernel(const float* __restrict__ ret, bf16* __restrict__ y) {
  const int d = threadIdx.x, l = blockIdx.x, h = blockIdx.y, b = blockIdx.z;
  float r = ret[((long long)(b*NH + h)*SEQ + l)*DQ + d];
  float s = r / (1.f + __expf(-r));
  wpair(y, ((long long)(b*SEQ + l)*NH + h)*DQ + d, PY, s);
}

// ---------------------------------------------------------------------------
extern "C" void kernel_launch(void* const* d_in, const int* in_sizes, int n_in,
                              void* d_out, int out_size, void* d_ws, size_t ws_size,
                              hipStream_t stream) {
  const float* x      = (const float*)d_in[0];
  const float* tin_w  = (const float*)d_in[1];
  const float* tin_b  = (const float*)d_in[2];
  const float* tout_w = (const float*)d_in[3];
  const float* tout_b = (const float*)d_in[4];
  const float* wq_w   = (const float*)d_in[5];
  const float* wq_b   = (const float*)d_in[6];
  const float* wk_w   = (const float*)d_in[7];
  const float* wk_b   = (const float*)d_in[8];
  const float* wv_w   = (const float*)d_in[9];
  const float* wv_b   = (const float*)d_in[10];
  const float* wo_w   = (const float*)d_in[11];
  const float* wo_b   = (const float*)d_in[12];
  const float* f1_w   = (const float*)d_in[13];
  const float* f1_b   = (const float*)d_in[14];
  const float* f2_w   = (const float*)d_in[15];
  const float* f2_b   = (const float*)d_in[16];
  const float* phz_re = (const float*)d_in[17];
  const float* phz_im = (const float*)d_in[18];
  const float* amp    = (const float*)d_in[19];
  const float* lc_re  = (const float*)d_in[20];
  const float* lc_im  = (const float*)d_in[21];
  (void)in_sizes; (void)n_in; (void)out_size; (void)ws_size;

  char* w = (char*)d_ws;
  auto alloc = [&](size_t bytes) {
    char* p = w; w += (bytes + 255) & ~(size_t)255; return p;
  };
  auto palloc = [&](long long elems) {
    return (bf16*)alloc((size_t)elems * 2 * 2);
  };

  const long long WP = 3LL*DIM*DIM;
  float* h     = (float*)alloc((size_t)ROWS*DIM*4);
  float* ret   = (float*)alloc((size_t)BATCH*NH*SEQ*DQ*4);
  float* qkvbi = (float*)alloc((size_t)3*DIM*4);
  float* dtab  = (float*)alloc((size_t)NH*(SEQ+1)*4);
  bf16*  hb    = palloc(PQKV);
  bf16*  Wqkv  = palloc(WP);
  bf16*  Wol   = palloc((long long)DIM*DIM);
  bf16*  Wf1l  = palloc((long long)DH*DIM);
  bf16*  Wf2l  = (bf16*)alloc((size_t)DIM*DH*2);
  bf16*  qkvb  = palloc(PQKV3);
  bf16*  lcc   = (bf16*)alloc((size_t)NH*DQ*2*DQ*2);
  bf16*  Wbig  = (bf16*)alloc((size_t)DIM*VOC*2);
  bf16*  qrot  = (bf16*)alloc((size_t)PROT*2);
  bf16*  krot  = (bf16*)alloc((size_t)PROT*2);
  bf16*  qwb   = (bf16*)alloc((size_t)PROT*2);
  bf16*  vtb   = (bf16*)alloc((size_t)PVT*2);
  bf16*  Sb    = (bf16*)alloc((size_t)PS*2);
  bf16*  mid   = palloc(PMID);
  bf16*  xb = (bf16*)d_out;
  bf16*  yb = qkvb;

  auto gemm = [&](int epi, int sa, int sb, const bf16* A, long long sA, long long pA, int lda,
                  const bf16* B, long long sB, long long pB, int ldb, int bmod,
                  void* C, long long sC, long long pC, int ldc,
                  const float* bias, int hmod, int M, int N, int K, int batch,
                  int ksplit, int causal) {
    dim3 g(M / BM, N / BN, batch * ksplit), blk(256);
    if (epi == 3 && !sa && !sb)      gemm_bt<3,0,0><<<g, blk, 0, stream>>>(A,sA,pA,lda,B,sB,pB,ldb,bmod,C,sC,pC,ldc,bias,hmod,M,N,K,ksplit,causal);
    else if (epi == 7)               gemm_bt<7,0,0><<<g, blk, 0, stream>>>(A,sA,pA,lda,B,sB,pB,ldb,bmod,C,sC,pC,ldc,bias,hmod,M,N,K,ksplit,causal);
    else if (epi == 3 && sa && !sb)  gemm_bt<3,1,0><<<g, blk, 0, stream>>>(A,sA,pA,lda,B,sB,pB,ldb,bmod,C,sC,pC,ldc,bias,hmod,M,N,K,ksplit,causal);
    else if (epi == 3)               gemm_bt<3,1,1><<<g, blk, 0, stream>>>(A,sA,pA,lda,B,sB,pB,ldb,bmod,C,sC,pC,ldc,bias,hmod,M,N,K,ksplit,causal);
    else if (epi == 5)               gemm_bt<5,1,1><<<g, blk, 0, stream>>>(A,sA,pA,lda,B,sB,pB,ldb,bmod,C,sC,pC,ldc,bias,hmod,M,N,K,ksplit,causal);
    else if (epi == 6)               gemm_bt<6,1,1><<<g, blk, 0, stream>>>(A,sA,pA,lda,B,sB,pB,ldb,bmod,C,sC,pC,ldc,bias,hmod,M,N,K,ksplit,causal);
  };
  const int BIG = 1 << 30;

  // ---- input projection: gemm256 split-K x10 (atomic into zeroed h) ----
  tinprep_kernel<<<dim3((unsigned)((TIN_H4 + 255) / 256)), dim3(256), 0, stream>>>(
      x, xb, tin_w, Wbig, (float4*)h);
  gemm256<3,1><<<dim3(ROWS/256, DIM/256, 10), dim3(512), 0, stream>>>(
      xb, 0, 0, VOC, Wbig, 0, 0, VOC, h, DIM, tin_b, ROWS, DIM, VOC, 10);

  for (int i = 0; i < DEPTH; ++i) {
    castw_kernel<<<dim3((unsigned)((12LL*DIM*DIM + 255) / 256)), dim3(256), 0, stream>>>(
        wq_w + (size_t)i*DIM*DIM, wk_w + (size_t)i*DIM*DIM, wv_w + (size_t)i*DIM*DIM,
        wo_w + (size_t)i*DIM*DIM, f1_w + (size_t)i*DH*DIM, f2_w + (size_t)i*DIM*DH,
        Wqkv, Wol, Wf1l, Wf2l);
    misc_kernel<<<dim3((unsigned)((MISC_ZR + 255) / 256)), dim3(256), 0, stream>>>(
        lc_re + (size_t)i*NH*DQ*DQ, lc_im + (size_t)i*NH*DQ*DQ, lcc,
        wq_b + i*DIM, wk_b + i*DIM, wv_b + i*DIM, qkvbi,
        amp + i*NH, dtab, (float4*)ret);

    // retention
    ln_kernel<<<ROWS, 256, 0, stream>>>(h, hb);
    gemm(5, 1, 1, hb, 0, PQKV, DIM, Wqkv, 0, WP, DIM, BIG,
         qkvb, 0, PQKV3, 3*DIM, qkvbi, 1, ROWS, 3*DIM, DIM, 1, 1, 0);
    rotate_kernel<<<dim3(SEQ, NH, BATCH), DQ, 0, stream>>>(
        qkvb, phz_re + i*NH*DQ, phz_im + i*NH*DQ, dtab, qrot, krot, qwb);
    vt_kernel<<<dim3(SEQ/64, DQ/64, BATCH*NH), 256, 0, stream>>>(qkvb, vtb);
    gemm(7, 0, 0, qrot, (long long)SEQ*2*DQ, 0, 2*DQ,
         krot, (long long)SEQ*2*DQ, 0, 2*DQ, BIG,
         Sb, (long long)SEQ*SEQ, 0, SEQ, dtab, NH, SEQ, SEQ, 2*DQ, BATCH*NH, 1, 1);
    gemm(3, 0, 0, Sb, (long long)SEQ*SEQ, 0, SEQ,
         vtb, (long long)DQ*SEQ, 0, SEQ, BIG,
         ret, (long long)SEQ*DQ, 0, DQ, nullptr, 1, SEQ, DQ, SEQ, BATCH*NH, 4, 2);
    gemm(3, 0, 0, qwb, (long long)SEQ*2*DQ, 0, 2*DQ,
         lcc, (long long)DQ*2*DQ, 0, 2*DQ, NH,
         ret, (long long)SEQ*DQ, 0, DQ, nullptr, 1, SEQ, DQ, 2*DQ, BATCH*NH, 2, 0);
    siluret_kernel<<<dim3(SEQ, NH, BATCH), DQ, 0, stream>>>(ret, yb);
    gemm(3, 1, 1, yb, 0, PY, DIM, Wol, 0, (long long)DIM*DIM, DIM, BIG,
         h, 0, 0, DIM, wo_b + i*DIM, 1, ROWS, DIM, DIM, 1, 2, 0);

    // FFN
    ln_kernel<<<ROWS, 256, 0, stream>>>(h, hb);
    gemm(6, 1, 1, hb, 0, PQKV, DIM, Wf1l, 0, (long long)DH*DIM, DIM, BIG,
         mid, 0, PMID, DH, f1_b + i*DH, 1, ROWS, DH, DIM, 1, 1, 0);
    gemm256<3,2><<<dim3(ROWS/256, DIM/256, 8), dim3(512), 0, stream>>>(
        mid, PMID, 0, DH, Wf2l, 0, 0, DH, h, DIM, f2_b + i*DIM, ROWS, DIM, DH, 8);
  }

  // ---- output projection: gemm256 2-pass (A=hb pair, B=tout_w hi) ----
  tailprep_kernel<<<dim3((unsigned)((TAIL_W + 255) / 256)), dim3(256), 0, stream>>>(
      h, hb, tout_w, Wbig);
  gemm256<0,2><<<dim3(ROWS/256, VOC/256, 1), dim3(512), 0, stream>>>(
      hb, PQKV, 0, DIM, Wbig, 0, 0, DIM, (float*)d_out, VOC, tout_b,
      ROWS, VOC, DIM, 1);
}

// Round 9
// 1925.140 us; speedup vs baseline: 1.0877x; 1.0791x over previous
//
#include <hip/hip_runtime.h>
#include <hip/hip_bf16.h>
#include <stdint.h>

#define DEPTH 4
#define DIM   1024
#define DH    4096
#define NH    8
#define DQ    128
#define VOC   32000
#define BATCH 2
#define SEQ   1024
#define ROWS  (BATCH*SEQ)   // 2048

#define PQKV  ((long long)ROWS*DIM)
#define PQKV3 ((long long)ROWS*3*DIM)
#define PROT  ((long long)BATCH*NH*SEQ*2*DQ)
#define PVT   ((long long)BATCH*NH*DQ*SEQ)
#define PS    ((long long)BATCH*NH*SEQ*SEQ)
#define PMID  ((long long)ROWS*DH)
#define PY    ((long long)ROWS*DIM)

typedef __hip_bfloat16 bf16;
using f32x4  = __attribute__((ext_vector_type(4))) float;
using bf16x8 = __attribute__((ext_vector_type(8))) __bf16;

__device__ __forceinline__ void wpair(bf16* p, long long off, long long plane, float v) {
  bf16 hi = __float2bfloat16(v);
  p[off] = hi;
  p[off + plane] = __float2bfloat16(v - __bfloat162float(hi));
}

__device__ __forceinline__ void gload_lds16(const void* g, void* l) {
  __builtin_amdgcn_global_load_lds(
      (const __attribute__((address_space(1))) void*)g,
      (__attribute__((address_space(3))) void*)(uintptr_t)l,
      16, 0, 0);
}

// XCD-aware bijective remap (m204): dispatch id f -> work id f'. Same-XCD
// blocks (f%8) get a contiguous chunk of work ids decoded m-fastest, so the
// ~16 m-blocks sharing one B n-panel co-reside on one XCD's L2. nwg%8==0
// for every grid used here.
__device__ __forceinline__ int2 xcd_remap(int gx, int gy) {
  int f   = blockIdx.x + gx * blockIdx.y;
  int nwg = gx * gy;
  int fp  = (f & 7) * (nwg >> 3) + (f >> 3);
  return int2{fp % gx, fp / gx};
}

// ---------------------------------------------------------------------------
// Batched GEMM: C[zb] = A[zb] (MxK rm) * B[zb%bmod]^T (NxK rm)
// Tile map: x = m-tiles (fastest), y = n-tiles, + XCD remap.
// blockIdx.z = zb*ksplit + kslice (Kc = K/ksplit columns).
// SA/SB: operand has a bf16 lo plane at +pA/+pB; passes = Ah*Bh [+Al*Bh] [+Ah*Bl].
// EPI 0: f32 C = acc+bias              3: f32 C += acc+bias (atomic if ksplit>1)
//     5: pair C = acc+bias             6: pair C = silu(acc+bias)
//     7: bf16 C = acc*decay, decay = dtab[(zb%hmod)*(SEQ+1) + (row-col)] (row>=col)
// causal: 1 = skip blocks fully above diagonal (S; skipped tiles never written)
//         2 = clamp K-loop to kend = tm+BM (PV reading causal S; skip if empty)
// bias added by slice 0 only.
// ---------------------------------------------------------------------------
#define BM 128
#define BN 128
#define BKK 64
#define PL 16384   // one LDS plane: 128 rows x 64 bf16

template<int EPI, int SA, int SB>
__global__ __launch_bounds__(256, (SA || SB) ? 2 : 4)
void gemm_bt(const bf16* __restrict__ A, long long sA, long long pA, int lda,
             const bf16* __restrict__ B, long long sB, long long pB, int ldb, int bmod,
             void* __restrict__ Cv, long long sC, long long pC, int ldc,
             const float* __restrict__ bias, int hmod,
             int M, int N, int K, int ksplit, int causal)
{
  __shared__ int4 sbuf[1024 * (2 + SA + SB)];
  char* Asb = (char*)sbuf;
  char* Bsb = Asb + PL * (1 + SA);

  const int tid  = threadIdx.x;
  const int lane = tid & 63;
  const int wave = tid >> 6;
  const int wr   = wave >> 1;
  const int wc   = wave & 1;
  const int z    = blockIdx.z;
  const int zb   = z / ksplit;
  const int ks   = z - zb * ksplit;
  const int Kc   = K / ksplit;
  const int k0   = ks * Kc;
  const int2 xy  = xcd_remap(gridDim.x, gridDim.y);
  const int tm   = xy.x * BM;
  const int tn   = xy.y * BN;

  if (causal == 1 && tn >= tm + BM) return;      // fully-masked S tile
  int kend = k0 + Kc;
  if (causal == 2) {                              // PV: only m < tm+BM valid
    kend = min(kend, tm + BM);
    if (kend <= k0) return;
  }

  const bf16* Ab = A + (long long)zb * sA;
  const bf16* Bb = B + (long long)(zb % bmod) * sB;

  f32x4 acc[4][4] = {};

  for (int kt = k0; kt < kend; kt += BKK) {
#pragma unroll
    for (int j = 0; j < 4; ++j) {
      int slot0 = j*256 + wave*64;          // wave-uniform LDS base
      int i = slot0 + lane;
      int row = i >> 3;
      int gc  = (i & 7) ^ (row & 7);        // inverse-swizzled global chunk
      long long ga = (long long)(tm + row) * lda + kt + gc*8;
      long long gb = (long long)(tn + row) * ldb + kt + gc*8;
      gload_lds16(Ab + ga, Asb + slot0*16);
      if (SA) gload_lds16(Ab + pA + ga, Asb + PL + slot0*16);
      gload_lds16(Bb + gb, Bsb + slot0*16);
      if (SB) gload_lds16(Bb + pB + gb, Bsb + PL + slot0*16);
    }
    __syncthreads();
#pragma unroll
    for (int kh = 0; kh < 2; ++kh) {
      const int cb = kh*4 + (lane >> 4);
      int4 avh[4], bvh[4], avl[4], bvl[4];
#pragma unroll
      for (int mi = 0; mi < 4; ++mi) {
        int m = wr*64 + mi*16 + (lane & 15);
        int off = m*128 + ((cb ^ (m & 7)) << 4);
        avh[mi] = *(const int4*)(Asb + off);
        if (SA) avl[mi] = *(const int4*)(Asb + PL + off);
      }
#pragma unroll
      for (int nj = 0; nj < 4; ++nj) {
        int n = wc*64 + nj*16 + (lane & 15);
        int off = n*128 + ((cb ^ (n & 7)) << 4);
        bvh[nj] = *(const int4*)(Bsb + off);
        if (SB) bvl[nj] = *(const int4*)(Bsb + PL + off);
      }
#pragma unroll
      for (int mi = 0; mi < 4; ++mi)
#pragma unroll
        for (int nj = 0; nj < 4; ++nj)
          acc[mi][nj] = __builtin_amdgcn_mfma_f32_16x16x32_bf16(
              __builtin_bit_cast(bf16x8, avh[mi]),
              __builtin_bit_cast(bf16x8, bvh[nj]), acc[mi][nj], 0, 0, 0);
      if (SA)
#pragma unroll
        for (int mi = 0; mi < 4; ++mi)
#pragma unroll
          for (int nj = 0; nj < 4; ++nj)
            acc[mi][nj] = __builtin_amdgcn_mfma_f32_16x16x32_bf16(
                __builtin_bit_cast(bf16x8, avl[mi]),
                __builtin_bit_cast(bf16x8, bvh[nj]), acc[mi][nj], 0, 0, 0);
      if (SB)
#pragma unroll
        for (int mi = 0; mi < 4; ++mi)
#pragma unroll
          for (int nj = 0; nj < 4; ++nj)
            acc[mi][nj] = __builtin_amdgcn_mfma_f32_16x16x32_bf16(
                __builtin_bit_cast(bf16x8, avh[mi]),
                __builtin_bit_cast(bf16x8, bvl[nj]), acc[mi][nj], 0, 0, 0);
    }
    __syncthreads();
  }

  const float* dtab = (EPI == 7) ? bias + (zb % hmod) * (SEQ + 1) : nullptr;
  const int col = lane & 15;
  const int rb  = (lane >> 4) << 2;
  float* Cf = (float*)Cv + (long long)zb * sC;
  bf16*  Ch = (bf16*) Cv + (long long)zb * sC;

#pragma unroll
  for (int mi = 0; mi < 4; ++mi)
#pragma unroll
    for (int nj = 0; nj < 4; ++nj) {
      long long gn = tn + wc*64 + nj*16 + col;
      float bv_ = (EPI != 7 && bias && ks == 0) ? bias[gn] : 0.f;
#pragma unroll
      for (int r = 0; r < 4; ++r) {
        long long gm = tm + wr*64 + mi*16 + rb + r;
        float v = acc[mi][nj][r] + bv_;
        long long off = gm * (long long)ldc + gn;
        if (EPI == 0)      Cf[off] = v;
        else if (EPI == 3) { if (ksplit > 1) atomicAdd(&Cf[off], v); else Cf[off] += v; }
        else if (EPI == 5) wpair(Ch, off, pC, v);
        else if (EPI == 6) wpair(Ch, off, pC, v / (1.f + __expf(-v)));
        else {
          long long dlt = gm - gn;
          float dcy = (dlt >= 0) ? dtab[dlt] : 0.f;
          Ch[off] = __float2bfloat16(acc[mi][nj][r] * dcy);
        }
      }
    }
}

// ---------------------------------------------------------------------------
__global__ void castw_kernel(const float* __restrict__ wq, const float* __restrict__ wk,
                             const float* __restrict__ wv, const float* __restrict__ wo,
                             const float* __restrict__ f1, const float* __restrict__ f2,
                             bf16* __restrict__ Wqkv, bf16* __restrict__ Wol,
                             bf16* __restrict__ Wf1, bf16* __restrict__ Wf2) {
  const long long S1 = (long long)DIM*DIM;
  const long long WP = 3*S1;
  long long i = (long long)blockIdx.x * blockDim.x + threadIdx.x;
  if (i < 3*S1) {
    const float* src = (i < S1) ? wq : (i < 2*S1) ? wk : wv;
    float v = src[i & (S1-1)];
    bf16 h = __float2bfloat16(v);
    Wqkv[i] = h;
    Wqkv[i + WP] = __float2bfloat16(v - __bfloat162float(h));
  } else if (i < 4*S1) {
    long long j = i - 3*S1;
    float v = wo[j];
    bf16 h = __float2bfloat16(v);
    Wol[j] = h;
    Wol[j + S1] = __float2bfloat16(v - __bfloat162float(h));
  } else if (i < 8*S1) {
    long long j = i - 4*S1;
    float v = f1[j];
    bf16 h = __float2bfloat16(v);
    Wf1[j] = h;
    Wf1[j + 4*S1] = __float2bfloat16(v - __bfloat162float(h));
  } else if (i < 12*S1) {
    long long j = i - 8*S1;
    Wf2[j] = __float2bfloat16(f2[j]);
  }
}

#define MISC_LC   (NH*DQ*DQ)
#define MISC_B3   (MISC_LC + 3*DIM)
#define MISC_DC   (MISC_B3 + NH*(SEQ+1))
#define MISC_ZR   (MISC_DC + (BATCH*NH*SEQ*DQ)/4)
__global__ void misc_kernel(const float* __restrict__ lcr, const float* __restrict__ lci,
                            bf16* __restrict__ lc,
                            const float* __restrict__ bq, const float* __restrict__ bk,
                            const float* __restrict__ bv, float* __restrict__ qkvbi,
                            const float* __restrict__ amp, float* __restrict__ dtab,
                            float4* __restrict__ retz) {
  long long i = (long long)blockIdx.x * blockDim.x + threadIdx.x;
  if (i < MISC_LC) {
    int d = i & 127, e = (i >> 7) & 127, h = i >> 14;
    float vr = lcr[((long long)h*DQ + d)*DQ + e];
    float vi = lci[((long long)h*DQ + d)*DQ + e];
    long long dst = ((long long)h*DQ + e)*(2*DQ) + d;
    lc[dst]      = __float2bfloat16(vr);
    lc[dst + DQ] = __float2bfloat16(-vi);
  } else if (i < MISC_B3) {
    int j = (int)(i - MISC_LC);
    qkvbi[j] = (j < DIM) ? bq[j] : (j < 2*DIM) ? bk[j - DIM] : bv[j - 2*DIM];
  } else if (i < MISC_DC) {
    int j = (int)(i - MISC_B3);
    int h = j / (SEQ+1), n = j % (SEQ+1);
    float a = 1.f / (1.f + __expf(-amp[h]));
    dtab[j] = powf(a, (float)n);
  } else if (i < MISC_ZR) {
    retz[i - MISC_DC] = float4{0.f, 0.f, 0.f, 0.f};
  }
}

#define TIN_X4 ((long long)ROWS*VOC/4)
#define TIN_W4 (TIN_X4 + (long long)DIM*VOC/4)
#define TIN_H4 (TIN_W4 + (long long)ROWS*DIM/4)
__global__ void tinprep_kernel(const float* __restrict__ x, bf16* __restrict__ xb,
                               const float* __restrict__ tw, bf16* __restrict__ twb,
                               float4* __restrict__ hz) {
  long long i = (long long)blockIdx.x * blockDim.x + threadIdx.x;
  const float* src; bf16* dst; long long j;
  if (i < TIN_X4)      { src = x;  dst = xb;  j = i; }
  else if (i < TIN_W4) { src = tw; dst = twb; j = i - TIN_X4; }
  else if (i < TIN_H4) { hz[i - TIN_W4] = float4{0.f,0.f,0.f,0.f}; return; }
  else return;
  float4 v = ((const float4*)src)[j];
  ushort4 o{__builtin_bit_cast(unsigned short, __float2bfloat16(v.x)),
            __builtin_bit_cast(unsigned short, __float2bfloat16(v.y)),
            __builtin_bit_cast(unsigned short, __float2bfloat16(v.z)),
            __builtin_bit_cast(unsigned short, __float2bfloat16(v.w))};
  ((ushort4*)dst)[j] = o;
}

#define TAIL_H (PQKV)
#define TAIL_W (TAIL_H + (long long)VOC*DIM/4)
__global__ void tailprep_kernel(const float* __restrict__ h, bf16* __restrict__ hb,
                                const float* __restrict__ tw, bf16* __restrict__ twb) {
  long long i = (long long)blockIdx.x * blockDim.x + threadIdx.x;
  if (i < TAIL_H) {
    float v = h[i];
    bf16 hi = __float2bfloat16(v);
    hb[i] = hi;
    hb[i + PQKV] = __float2bfloat16(v - __bfloat162float(hi));
  } else if (i < TAIL_W) {
    long long j = i - TAIL_H;
    float4 v = ((const float4*)tw)[j];
    ushort4 o{__builtin_bit_cast(unsigned short, __float2bfloat16(v.x)),
              __builtin_bit_cast(unsigned short, __float2bfloat16(v.y)),
              __builtin_bit_cast(unsigned short, __float2bfloat16(v.z)),
              __builtin_bit_cast(unsigned short, __float2bfloat16(v.w))};
    ((ushort4*)twb)[j] = o;
  }
}

__global__ void ln_kernel(const float* __restrict__ in, bf16* __restrict__ out) {
  const int row = blockIdx.x;
  const int tid = threadIdx.x;          // 256
  const float4 v = ((const float4*)(in + (size_t)row*DIM))[tid];
  float s  = v.x + v.y + v.z + v.w;
  float s2 = v.x*v.x + v.y*v.y + v.z*v.z + v.w*v.w;
#pragma unroll
  for (int o = 32; o > 0; o >>= 1) { s += __shfl_xor(s, o); s2 += __shfl_xor(s2, o); }
  __shared__ float red[8];
  const int wv = tid >> 6;
  if ((tid & 63) == 0) { red[wv] = s; red[4 + wv] = s2; }
  __syncthreads();
  s  = red[0] + red[1] + red[2] + red[3];
  s2 = red[4] + red[5] + red[6] + red[7];
  const float mean = s * (1.f / DIM);
  const float var  = s2 * (1.f / DIM) - mean * mean;
  const float inv  = rsqrtf(var + 1e-5f);
  long long base = (long long)row*DIM + tid*4;
  wpair(out, base + 0, PQKV, (v.x - mean) * inv);
  wpair(out, base + 1, PQKV, (v.y - mean) * inv);
  wpair(out, base + 2, PQKV, (v.z - mean) * inv);
  wpair(out, base + 3, PQKV, (v.w - mean) * inv);
}

__global__ void rotate_kernel(const bf16* __restrict__ qkv,
                              const float* __restrict__ pre, const float* __restrict__ pim,
                              const float* __restrict__ dtab,
                              bf16* __restrict__ qrot, bf16* __restrict__ krot,
                              bf16* __restrict__ qwb) {
  const int d = threadIdx.x, l = blockIdx.x, h = blockIdx.y, b = blockIdx.z;
  const float tr = pre[h*DQ + d], ti = pim[h*DQ + d];
  const float theta = atan2f(ti, tr);
  const long long rowb = (long long)(b*SEQ + l)*(3*DIM) + h*DQ + d;
  const float qv = __bfloat162float(qkv[rowb]) + __bfloat162float(qkv[rowb + PQKV3]);
  const float kv = __bfloat162float(qkv[rowb + DIM]) + __bfloat162float(qkv[rowb + DIM + PQKV3]);
  float sn, cs;
  sincosf(theta * (float)l, &sn, &cs);
  const long long dst = ((long long)(b*NH + h)*SEQ + l)*(2*DQ) + d;
  qrot[dst]      = __float2bfloat16(qv * cs);
  qrot[dst + DQ] = __float2bfloat16(qv * sn);
  krot[dst]      = __float2bfloat16(kv * cs);
  krot[dst + DQ] = __float2bfloat16(kv * sn);
  float sn2, cs2;
  sincosf(theta * (float)(l + 1), &sn2, &cs2);
  const float ad = dtab[h*(SEQ+1) + l + 1];
  qwb[dst]      = __float2bfloat16(qv * ad * cs2);
  qwb[dst + DQ] = __float2bfloat16(qv * ad * sn2);
}

__global__ void vt_kernel(const bf16* __restrict__ qkv, bf16* __restrict__ vt) {
  __shared__ float tile[64][65];
  const int t  = threadIdx.x;           // 256
  const int c  = t & 63, r4 = t >> 6;
  const int m0 = blockIdx.x * 64;
  const int d0 = blockIdx.y * 64;
  const int h  = blockIdx.z & (NH - 1);
  const int b  = blockIdx.z >> 3;
#pragma unroll
  for (int rr = 0; rr < 64; rr += 4) {
    const int m = m0 + rr + r4;
    const long long src = (long long)(b*SEQ + m)*(3*DIM) + 2*DIM + h*DQ + d0 + c;
    tile[rr + r4][c] = __bfloat162float(qkv[src]) + __bfloat162float(qkv[src + PQKV3]);
  }
  __syncthreads();
#pragma unroll
  for (int rr = 0; rr < 64; rr += 4) {
    const int d = rr + r4;
    vt[((long long)(b*NH + h)*DQ + d0 + d)*SEQ + m0 + c] = __float2bfloat16(tile[c][d]);
  }
}

__global__ void siluret_kernel(const float* __restrict__ ret, bf16* __restrict__ y) {
  const int d = threadIdx.x, l = blockIdx.x, h = blockIdx.y, b = blockIdx.z;
  float r = ret[((long long)(b*NH + h)*SEQ + l)*DQ + d];
  float s = r / (1.f + __expf(-r));
  wpair(y, ((long long)(b*SEQ + l)*NH + h)*DQ + d, PY, s);
}

// ---------------------------------------------------------------------------
extern "C" void kernel_launch(void* const* d_in, const int* in_sizes, int n_in,
                              void* d_out, int out_size, void* d_ws, size_t ws_size,
                              hipStream_t stream) {
  const float* x      = (const float*)d_in[0];
  const float* tin_w  = (const float*)d_in[1];
  const float* tin_b  = (const float*)d_in[2];
  const float* tout_w = (const float*)d_in[3];
  const float* tout_b = (const float*)d_in[4];
  const float* wq_w   = (const float*)d_in[5];
  const float* wq_b   = (const float*)d_in[6];
  const float* wk_w   = (const float*)d_in[7];
  const float* wk_b   = (const float*)d_in[8];
  const float* wv_w   = (const float*)d_in[9];
  const float* wv_b   = (const float*)d_in[10];
  const float* wo_w   = (const float*)d_in[11];
  const float* wo_b   = (const float*)d_in[12];
  const float* f1_w   = (const float*)d_in[13];
  const float* f1_b   = (const float*)d_in[14];
  const float* f2_w   = (const float*)d_in[15];
  const float* f2_b   = (const float*)d_in[16];
  const float* phz_re = (const float*)d_in[17];
  const float* phz_im = (const float*)d_in[18];
  const float* amp    = (const float*)d_in[19];
  const float* lc_re  = (const float*)d_in[20];
  const float* lc_im  = (const float*)d_in[21];
  (void)in_sizes; (void)n_in; (void)out_size; (void)ws_size;

  char* w = (char*)d_ws;
  auto alloc = [&](size_t bytes) {
    char* p = w; w += (bytes + 255) & ~(size_t)255; return p;
  };
  auto palloc = [&](long long elems) {       // hi/lo pair, lo at +elems
    return (bf16*)alloc((size_t)elems * 2 * 2);
  };

  const long long WP = 3LL*DIM*DIM;
  float* h     = (float*)alloc((size_t)ROWS*DIM*4);
  float* ret   = (float*)alloc((size_t)BATCH*NH*SEQ*DQ*4);
  float* qkvbi = (float*)alloc((size_t)3*DIM*4);
  float* dtab  = (float*)alloc((size_t)NH*(SEQ+1)*4);
  bf16*  hb    = palloc(PQKV);
  bf16*  Wqkv  = palloc(WP);
  bf16*  Wol   = palloc((long long)DIM*DIM);
  bf16*  Wf1l  = palloc((long long)DH*DIM);
  bf16*  Wf2l  = (bf16*)alloc((size_t)DIM*DH*2);     // hi only (2-pass f2)
  bf16*  qkvb  = palloc(PQKV3);
  bf16*  lcc   = (bf16*)alloc((size_t)NH*DQ*2*DQ*2); // single plane
  bf16*  Wbig  = (bf16*)alloc((size_t)DIM*VOC*2);    // hi only (tin + 2-pass tout)
  bf16*  qrot  = (bf16*)alloc((size_t)PROT*2);       // single plane
  bf16*  krot  = (bf16*)alloc((size_t)PROT*2);       // single plane
  bf16*  qwb   = (bf16*)alloc((size_t)PROT*2);       // single plane
  bf16*  vtb   = (bf16*)alloc((size_t)PVT*2);        // single plane
  bf16*  Sb    = (bf16*)alloc((size_t)PS*2);         // single plane
  bf16*  mid   = palloc(PMID);
  // aliases (lifetimes disjoint):
  bf16*  xb = (bf16*)d_out;    // bf16 x in d_out; dead before tout writes
  bf16*  yb = qkvb;            // silu(ret) pair; qkvb dead after rotate/vt

  // grid: x = m-tiles (fastest), y = n-tiles, z = batch*ksplit; XCD remap inside
  auto gemm = [&](int epi, int sa, int sb, const bf16* A, long long sA, long long pA, int lda,
                  const bf16* B, long long sB, long long pB, int ldb, int bmod,
                  void* C, long long sC, long long pC, int ldc,
                  const float* bias, int hmod, int M, int N, int K, int batch,
                  int ksplit, int causal) {
    dim3 g(M / BM, N / BN, batch * ksplit), blk(256);
    if (epi == 3 && !sa && !sb)      gemm_bt<3,0,0><<<g, blk, 0, stream>>>(A,sA,pA,lda,B,sB,pB,ldb,bmod,C,sC,pC,ldc,bias,hmod,M,N,K,ksplit,causal);
    else if (epi == 7)               gemm_bt<7,0,0><<<g, blk, 0, stream>>>(A,sA,pA,lda,B,sB,pB,ldb,bmod,C,sC,pC,ldc,bias,hmod,M,N,K,ksplit,causal);
    else if (epi == 0 && sa && !sb)  gemm_bt<0,1,0><<<g, blk, 0, stream>>>(A,sA,pA,lda,B,sB,pB,ldb,bmod,C,sC,pC,ldc,bias,hmod,M,N,K,ksplit,causal);
    else if (epi == 3 && sa && !sb)  gemm_bt<3,1,0><<<g, blk, 0, stream>>>(A,sA,pA,lda,B,sB,pB,ldb,bmod,C,sC,pC,ldc,bias,hmod,M,N,K,ksplit,causal);
    else if (epi == 3)               gemm_bt<3,1,1><<<g, blk, 0, stream>>>(A,sA,pA,lda,B,sB,pB,ldb,bmod,C,sC,pC,ldc,bias,hmod,M,N,K,ksplit,causal);
    else if (epi == 5)               gemm_bt<5,1,1><<<g, blk, 0, stream>>>(A,sA,pA,lda,B,sB,pB,ldb,bmod,C,sC,pC,ldc,bias,hmod,M,N,K,ksplit,causal);
    else if (epi == 6)               gemm_bt<6,1,1><<<g, blk, 0, stream>>>(A,sA,pA,lda,B,sB,pB,ldb,bmod,C,sC,pC,ldc,bias,hmod,M,N,K,ksplit,causal);
  };
  const int BIG = 1 << 30;

  // ---- input projection: h = x @ tin_w^T + tin_b  (split-K x10, atomic) ----
  tinprep_kernel<<<dim3((unsigned)((TIN_H4 + 255) / 256)), dim3(256), 0, stream>>>(
      x, xb, tin_w, Wbig, (float4*)h);
  gemm(3, 0, 0, xb, 0, 0, VOC, Wbig, 0, 0, VOC, BIG, h, 0, 0, DIM, tin_b, 1,
       ROWS, DIM, VOC, 1, 10, 0);

  for (int i = 0; i < DEPTH; ++i) {
    castw_kernel<<<dim3((unsigned)((12LL*DIM*DIM + 255) / 256)), dim3(256), 0, stream>>>(
        wq_w + (size_t)i*DIM*DIM, wk_w + (size_t)i*DIM*DIM, wv_w + (size_t)i*DIM*DIM,
        wo_w + (size_t)i*DIM*DIM, f1_w + (size_t)i*DH*DIM, f2_w + (size_t)i*DIM*DH,
        Wqkv, Wol, Wf1l, Wf2l);
    misc_kernel<<<dim3((unsigned)((MISC_ZR + 255) / 256)), dim3(256), 0, stream>>>(
        lc_re + (size_t)i*NH*DQ*DQ, lc_im + (size_t)i*NH*DQ*DQ, lcc,
        wq_b + i*DIM, wk_b + i*DIM, wv_b + i*DIM, qkvbi,
        amp + i*NH, dtab, (float4*)ret);

    // retention
    ln_kernel<<<ROWS, 256, 0, stream>>>(h, hb);
    // fused qkv = hb @ [Wq;Wk;Wv]^T + [bq;bk;bv]  (3-pass)
    gemm(5, 1, 1, hb, 0, PQKV, DIM, Wqkv, 0, WP, DIM, BIG,
         qkvb, 0, PQKV3, 3*DIM, qkvbi, 1, ROWS, 3*DIM, DIM, 1, 1, 0);
    rotate_kernel<<<dim3(SEQ, NH, BATCH), DQ, 0, stream>>>(
        qkvb, phz_re + i*NH*DQ, phz_im + i*NH*DQ, dtab, qrot, krot, qwb);
    vt_kernel<<<dim3(SEQ/64, DQ/64, BATCH*NH), 256, 0, stream>>>(qkvb, vtb);
    // S = (Qrot Krot^T) * decay-mask   (1-pass, causal tile-skip)
    gemm(7, 0, 0, qrot, (long long)SEQ*2*DQ, 0, 2*DQ,
         krot, (long long)SEQ*2*DQ, 0, 2*DQ, BIG,
         Sb, (long long)SEQ*SEQ, 0, SEQ, dtab, NH, SEQ, SEQ, 2*DQ, BATCH*NH, 1, 1);
    // ret = S @ V (1-pass, split-K x4, atomic, causal K-clamp) + cross (x2)
    gemm(3, 0, 0, Sb, (long long)SEQ*SEQ, 0, SEQ,
         vtb, (long long)DQ*SEQ, 0, SEQ, BIG,
         ret, (long long)SEQ*DQ, 0, DQ, nullptr, 1, SEQ, DQ, SEQ, BATCH*NH, 4, 2);
    gemm(3, 0, 0, qwb, (long long)SEQ*2*DQ, 0, 2*DQ,
         lcc, (long long)DQ*2*DQ, 0, 2*DQ, NH,
         ret, (long long)SEQ*DQ, 0, DQ, nullptr, 1, SEQ, DQ, 2*DQ, BATCH*NH, 2, 0);
    siluret_kernel<<<dim3(SEQ, NH, BATCH), DQ, 0, stream>>>(ret, yb);
    // h += y @ wo^T + wo_b   (3-pass, split-K x2)
    gemm(3, 1, 1, yb, 0, PY, DIM, Wol, 0, (long long)DIM*DIM, DIM, BIG,
         h, 0, 0, DIM, wo_b + i*DIM, 1, ROWS, DIM, DIM, 1, 2, 0);

    // FFN
    ln_kernel<<<ROWS, 256, 0, stream>>>(h, hb);
    gemm(6, 1, 1, hb, 0, PQKV, DIM, Wf1l, 0, (long long)DH*DIM, DIM, BIG,
         mid, 0, PMID, DH, f1_b + i*DH, 1, ROWS, DH, DIM, 1, 1, 0);
    // f2: 2-pass (A=mid pair, B=Wf2 hi only), split-K x4
    gemm(3, 1, 0, mid, 0, PMID, DH, Wf2l, 0, 0, DH, BIG,
         h, 0, 0, DIM, f2_b + i*DIM, 1, ROWS, DIM, DH, 1, 4, 0);
  }

  // ---- output projection: 2-pass (A=hb pair, B=tout_w hi only) ----
  tailprep_kernel<<<dim3((unsigned)((TAIL_W + 255) / 256)), dim3(256), 0, stream>>>(
      h, hb, tout_w, Wbig);
  gemm(0, 1, 0, hb, 0, PQKV, DIM, Wbig, 0, 0, DIM, BIG,
       (float*)d_out, 0, 0, VOC, tout_b, 1, ROWS, VOC, DIM, 1, 1, 0);
}

// Round 10
// 1813.986 us; speedup vs baseline: 1.1544x; 1.0613x over previous
//
#include <hip/hip_runtime.h>
#include <hip/hip_bf16.h>
#include <stdint.h>

#define DEPTH 4
#define DIM   1024
#define DH    4096
#define NH    8
#define DQ    128
#define VOC   32000
#define BATCH 2
#define SEQ   1024
#define ROWS  (BATCH*SEQ)   // 2048

#define PQKV  ((long long)ROWS*DIM)
#define PQKV3 ((long long)ROWS*3*DIM)
#define PROT  ((long long)BATCH*NH*SEQ*2*DQ)
#define PVT   ((long long)BATCH*NH*DQ*SEQ)
#define PS    ((long long)BATCH*NH*SEQ*SEQ)
#define PMID  ((long long)ROWS*DH)
#define PY    ((long long)ROWS*DIM)

typedef __hip_bfloat16 bf16;
using f32x4  = __attribute__((ext_vector_type(4))) float;
using bf16x8 = __attribute__((ext_vector_type(8))) __bf16;

__device__ __forceinline__ unsigned short bcu(bf16 h) {
  return __builtin_bit_cast(unsigned short, h);
}

__device__ __forceinline__ void wpair(bf16* p, long long off, long long plane, float v) {
  bf16 hi = __float2bfloat16(v);
  p[off] = hi;
  p[off + plane] = __float2bfloat16(v - __bfloat162float(hi));
}

__device__ __forceinline__ void gload_lds16(const void* g, void* l) {
  __builtin_amdgcn_global_load_lds(
      (const __attribute__((address_space(1))) void*)g,
      (__attribute__((address_space(3))) void*)(uintptr_t)l,
      16, 0, 0);
}

// ---------------------------------------------------------------------------
// Batched GEMM: C[zb] = A[zb] (MxK rm) * B[zb%bmod]^T (NxK rm)
// Tile map: x = m-tiles (fastest -> blocks sharing a B panel dispatch
// together; L3 holds the panel working set), y = n-tiles.
// blockIdx.z = zb*ksplit + kslice (Kc = K/ksplit columns).
// SA/SB: operand has a bf16 lo plane at +pA/+pB; passes = Ah*Bh [+Al*Bh] [+Ah*Bl].
// EPI 0: f32 C = acc+bias              3: f32 C += acc+bias (atomic if ksplit>1)
//     5: pair C = acc+bias             6: pair C = silu(acc+bias)
//     7: bf16 C = acc*decay, decay = dtab[(zb%hmod)*(SEQ+1) + (row-col)] (row>=col)
// causal: 1 = skip blocks fully above diagonal (S; skipped tiles never written)
//         2 = clamp K-loop to kend = tm+BM (PV reading causal S; skip if empty)
// bias added by slice 0 only.
// ---------------------------------------------------------------------------
#define BM 128
#define BN 128
#define BKK 64
#define PL 16384   // one LDS plane: 128 rows x 64 bf16

template<int EPI, int SA, int SB>
__global__ __launch_bounds__(256, (SA || SB) ? 2 : 4)
void gemm_bt(const bf16* __restrict__ A, long long sA, long long pA, int lda,
             const bf16* __restrict__ B, long long sB, long long pB, int ldb, int bmod,
             void* __restrict__ Cv, long long sC, long long pC, int ldc,
             const float* __restrict__ bias, int hmod,
             int M, int N, int K, int ksplit, int causal)
{
  __shared__ int4 sbuf[1024 * (2 + SA + SB)];
  char* Asb = (char*)sbuf;
  char* Bsb = Asb + PL * (1 + SA);

  const int tid  = threadIdx.x;
  const int lane = tid & 63;
  const int wave = tid >> 6;
  const int wr   = wave >> 1;
  const int wc   = wave & 1;
  const int z    = blockIdx.z;
  const int zb   = z / ksplit;
  const int ks   = z - zb * ksplit;
  const int Kc   = K / ksplit;
  const int k0   = ks * Kc;
  const int tm   = blockIdx.x * BM;
  const int tn   = blockIdx.y * BN;

  if (causal == 1 && tn >= tm + BM) return;      // fully-masked S tile
  int kend = k0 + Kc;
  if (causal == 2) {                              // PV: only m < tm+BM valid
    kend = min(kend, tm + BM);
    if (kend <= k0) return;
  }

  const bf16* Ab = A + (long long)zb * sA;
  const bf16* Bb = B + (long long)(zb % bmod) * sB;

  f32x4 acc[4][4] = {};

  for (int kt = k0; kt < kend; kt += BKK) {
#pragma unroll
    for (int j = 0; j < 4; ++j) {
      int slot0 = j*256 + wave*64;          // wave-uniform LDS base
      int i = slot0 + lane;
      int row = i >> 3;
      int gc  = (i & 7) ^ (row & 7);        // inverse-swizzled global chunk
      long long ga = (long long)(tm + row) * lda + kt + gc*8;
      long long gb = (long long)(tn + row) * ldb + kt + gc*8;
      gload_lds16(Ab + ga, Asb + slot0*16);
      if (SA) gload_lds16(Ab + pA + ga, Asb + PL + slot0*16);
      gload_lds16(Bb + gb, Bsb + slot0*16);
      if (SB) gload_lds16(Bb + pB + gb, Bsb + PL + slot0*16);
    }
    __syncthreads();
#pragma unroll
    for (int kh = 0; kh < 2; ++kh) {
      const int cb = kh*4 + (lane >> 4);
      int4 avh[4], bvh[4], avl[4], bvl[4];
#pragma unroll
      for (int mi = 0; mi < 4; ++mi) {
        int m = wr*64 + mi*16 + (lane & 15);
        int off = m*128 + ((cb ^ (m & 7)) << 4);
        avh[mi] = *(const int4*)(Asb + off);
        if (SA) avl[mi] = *(const int4*)(Asb + PL + off);
      }
#pragma unroll
      for (int nj = 0; nj < 4; ++nj) {
        int n = wc*64 + nj*16 + (lane & 15);
        int off = n*128 + ((cb ^ (n & 7)) << 4);
        bvh[nj] = *(const int4*)(Bsb + off);
        if (SB) bvl[nj] = *(const int4*)(Bsb + PL + off);
      }
#pragma unroll
      for (int mi = 0; mi < 4; ++mi)
#pragma unroll
        for (int nj = 0; nj < 4; ++nj)
          acc[mi][nj] = __builtin_amdgcn_mfma_f32_16x16x32_bf16(
              __builtin_bit_cast(bf16x8, avh[mi]),
              __builtin_bit_cast(bf16x8, bvh[nj]), acc[mi][nj], 0, 0, 0);
      if (SA)
#pragma unroll
        for (int mi = 0; mi < 4; ++mi)
#pragma unroll
          for (int nj = 0; nj < 4; ++nj)
            acc[mi][nj] = __builtin_amdgcn_mfma_f32_16x16x32_bf16(
                __builtin_bit_cast(bf16x8, avl[mi]),
                __builtin_bit_cast(bf16x8, bvh[nj]), acc[mi][nj], 0, 0, 0);
      if (SB)
#pragma unroll
        for (int mi = 0; mi < 4; ++mi)
#pragma unroll
          for (int nj = 0; nj < 4; ++nj)
            acc[mi][nj] = __builtin_amdgcn_mfma_f32_16x16x32_bf16(
                __builtin_bit_cast(bf16x8, avh[mi]),
                __builtin_bit_cast(bf16x8, bvl[nj]), acc[mi][nj], 0, 0, 0);
    }
    __syncthreads();
  }

  const float* dtab = (EPI == 7) ? bias + (zb % hmod) * (SEQ + 1) : nullptr;
  const int col = lane & 15;
  const int rb  = (lane >> 4) << 2;
  float* Cf = (float*)Cv + (long long)zb * sC;
  bf16*  Ch = (bf16*) Cv + (long long)zb * sC;

#pragma unroll
  for (int mi = 0; mi < 4; ++mi)
#pragma unroll
    for (int nj = 0; nj < 4; ++nj) {
      long long gn = tn + wc*64 + nj*16 + col;
      float bv_ = (EPI != 7 && bias && ks == 0) ? bias[gn] : 0.f;
#pragma unroll
      for (int r = 0; r < 4; ++r) {
        long long gm = tm + wr*64 + mi*16 + rb + r;
        float v = acc[mi][nj][r] + bv_;
        long long off = gm * (long long)ldc + gn;
        if (EPI == 0)      Cf[off] = v;
        else if (EPI == 3) { if (ksplit > 1) atomicAdd(&Cf[off], v); else Cf[off] += v; }
        else if (EPI == 5) wpair(Ch, off, pC, v);
        else if (EPI == 6) wpair(Ch, off, pC, v / (1.f + __expf(-v)));
        else {
          long long dlt = gm - gn;
          float dcy = (dlt >= 0) ? dtab[dlt] : 0.f;
          Ch[off] = __float2bfloat16(acc[mi][nj][r] * dcy);
        }
      }
    }
}

// ---------------------------------------------------------------------------
// Fused per-layer weight cast, float4-vectorized (4 elems/thread):
// Wqkv pair (3M), Wol pair (1M), Wf1 pair (4M), Wf2 single (4M).
// Grid covers 12*S4 float4s.
__global__ void castw_kernel(const float* __restrict__ wq, const float* __restrict__ wk,
                             const float* __restrict__ wv, const float* __restrict__ wo,
                             const float* __restrict__ f1, const float* __restrict__ f2,
                             bf16* __restrict__ Wqkv, bf16* __restrict__ Wol,
                             bf16* __restrict__ Wf1, bf16* __restrict__ Wf2) {
  const long long S1 = (long long)DIM*DIM;   // 1M elems
  const long long S4 = S1 >> 2;              // float4s per S1
  const long long WP = 3*S1;
  long long i = (long long)blockIdx.x * blockDim.x + threadIdx.x;
  const float* src; bf16 *hi, *lo; long long j4;
  if (i < 3*S4) {
    int t = (int)(i / S4);
    src = (t == 0) ? wq : (t == 1) ? wk : wv;
    j4 = i - (long long)t * S4;
    hi = Wqkv + (long long)t * S1; lo = hi + WP;
  } else if (i < 4*S4)  { src = wo; j4 = i - 3*S4; hi = Wol; lo = Wol + S1; }
  else if (i < 8*S4)    { src = f1; j4 = i - 4*S4; hi = Wf1; lo = Wf1 + 4*S1; }
  else if (i < 12*S4)   { src = f2; j4 = i - 8*S4; hi = Wf2; lo = nullptr; }
  else return;
  float4 v = ((const float4*)src)[j4];
  bf16 h0 = __float2bfloat16(v.x), h1 = __float2bfloat16(v.y);
  bf16 h2 = __float2bfloat16(v.z), h3 = __float2bfloat16(v.w);
  ((ushort4*)hi)[j4] = ushort4{bcu(h0), bcu(h1), bcu(h2), bcu(h3)};
  if (lo) {
    bf16 l0 = __float2bfloat16(v.x - __bfloat162float(h0));
    bf16 l1 = __float2bfloat16(v.y - __bfloat162float(h1));
    bf16 l2 = __float2bfloat16(v.z - __bfloat162float(h2));
    bf16 l3 = __float2bfloat16(v.w - __bfloat162float(h3));
    ((ushort4*)lo)[j4] = ushort4{bcu(l0), bcu(l1), bcu(l2), bcu(l3)};
  }
}

// Fused per-layer misc prep: lccat (131072) + bias3 (3072) + decay (8*1025)
// + zero ret (524288 float4) in one launch.
#define MISC_LC   (NH*DQ*DQ)                 // 131072
#define MISC_B3   (MISC_LC + 3*DIM)          // +3072
#define MISC_DC   (MISC_B3 + NH*(SEQ+1))     // +8200
#define MISC_ZR   (MISC_DC + (BATCH*NH*SEQ*DQ)/4)
__global__ void misc_kernel(const float* __restrict__ lcr, const float* __restrict__ lci,
                            bf16* __restrict__ lc,
                            const float* __restrict__ bq, const float* __restrict__ bk,
                            const float* __restrict__ bv, float* __restrict__ qkvbi,
                            const float* __restrict__ amp, float* __restrict__ dtab,
                            float4* __restrict__ retz) {
  long long i = (long long)blockIdx.x * blockDim.x + threadIdx.x;
  if (i < MISC_LC) {
    int d = i & 127, e = (i >> 7) & 127, h = i >> 14;
    float vr = lcr[((long long)h*DQ + d)*DQ + e];
    float vi = lci[((long long)h*DQ + d)*DQ + e];
    long long dst = ((long long)h*DQ + e)*(2*DQ) + d;
    lc[dst]      = __float2bfloat16(vr);
    lc[dst + DQ] = __float2bfloat16(-vi);
  } else if (i < MISC_B3) {
    int j = (int)(i - MISC_LC);
    qkvbi[j] = (j < DIM) ? bq[j] : (j < 2*DIM) ? bk[j - DIM] : bv[j - 2*DIM];
  } else if (i < MISC_DC) {
    int j = (int)(i - MISC_B3);
    int h = j / (SEQ+1), n = j % (SEQ+1);
    float a = 1.f / (1.f + __expf(-amp[h]));
    dtab[j] = powf(a, (float)n);
  } else if (i < MISC_ZR) {
    retz[i - MISC_DC] = float4{0.f, 0.f, 0.f, 0.f};
  }
}

// tin prep: cast x (4-wide), cast tin_w (4-wide), zero h (float4), one launch.
#define TIN_X4 ((long long)ROWS*VOC/4)
#define TIN_W4 (TIN_X4 + (long long)DIM*VOC/4)
#define TIN_H4 (TIN_W4 + (long long)ROWS*DIM/4)
__global__ void tinprep_kernel(const float* __restrict__ x, bf16* __restrict__ xb,
                               const float* __restrict__ tw, bf16* __restrict__ twb,
                               float4* __restrict__ hz) {
  long long i = (long long)blockIdx.x * blockDim.x + threadIdx.x;
  const float* src; bf16* dst; long long j;
  if (i < TIN_X4)      { src = x;  dst = xb;  j = i; }
  else if (i < TIN_W4) { src = tw; dst = twb; j = i - TIN_X4; }
  else if (i < TIN_H4) { hz[i - TIN_W4] = float4{0.f,0.f,0.f,0.f}; return; }
  else return;
  float4 v = ((const float4*)src)[j];
  ushort4 o{bcu(__float2bfloat16(v.x)), bcu(__float2bfloat16(v.y)),
            bcu(__float2bfloat16(v.z)), bcu(__float2bfloat16(v.w))};
  ((ushort4*)dst)[j] = o;
}

// tail prep: pair-cast h -> hb + cast tout_w (4-wide), one launch.
#define TAIL_H (PQKV)
#define TAIL_W (TAIL_H + (long long)VOC*DIM/4)
__global__ void tailprep_kernel(const float* __restrict__ h, bf16* __restrict__ hb,
                                const float* __restrict__ tw, bf16* __restrict__ twb) {
  long long i = (long long)blockIdx.x * blockDim.x + threadIdx.x;
  if (i < TAIL_H) {
    float v = h[i];
    bf16 hi = __float2bfloat16(v);
    hb[i] = hi;
    hb[i + PQKV] = __float2bfloat16(v - __bfloat162float(hi));
  } else if (i < TAIL_W) {
    long long j = i - TAIL_H;
    float4 v = ((const float4*)tw)[j];
    ushort4 o{bcu(__float2bfloat16(v.x)), bcu(__float2bfloat16(v.y)),
              bcu(__float2bfloat16(v.z)), bcu(__float2bfloat16(v.w))};
    ((ushort4*)twb)[j] = o;
  }
}

__global__ void ln_kernel(const float* __restrict__ in, bf16* __restrict__ out) {
  const int row = blockIdx.x;
  const int tid = threadIdx.x;          // 256
  const float4 v = ((const float4*)(in + (size_t)row*DIM))[tid];
  float s  = v.x + v.y + v.z + v.w;
  float s2 = v.x*v.x + v.y*v.y + v.z*v.z + v.w*v.w;
#pragma unroll
  for (int o = 32; o > 0; o >>= 1) { s += __shfl_xor(s, o); s2 += __shfl_xor(s2, o); }
  __shared__ float red[8];
  const int wv = tid >> 6;
  if ((tid & 63) == 0) { red[wv] = s; red[4 + wv] = s2; }
  __syncthreads();
  s  = red[0] + red[1] + red[2] + red[3];
  s2 = red[4] + red[5] + red[6] + red[7];
  const float mean = s * (1.f / DIM);
  const float var  = s2 * (1.f / DIM) - mean * mean;
  const float inv  = rsqrtf(var + 1e-5f);
  long long base = (long long)row*DIM + tid*4;
  wpair(out, base + 0, PQKV, (v.x - mean) * inv);
  wpair(out, base + 1, PQKV, (v.y - mean) * inv);
  wpair(out, base + 2, PQKV, (v.z - mean) * inv);
  wpair(out, base + 3, PQKV, (v.w - mean) * inv);
}

// qkv pair [B,L,3*DIM] -> qrot/krot/qwb single-plane [B,H,L,2*DQ]
__global__ void rotate_kernel(const bf16* __restrict__ qkv,
                              const float* __restrict__ pre, const float* __restrict__ pim,
                              const float* __restrict__ dtab,
                              bf16* __restrict__ qrot, bf16* __restrict__ krot,
                              bf16* __restrict__ qwb) {
  const int d = threadIdx.x, l = blockIdx.x, h = blockIdx.y, b = blockIdx.z;
  const float tr = pre[h*DQ + d], ti = pim[h*DQ + d];
  const float theta = atan2f(ti, tr);
  const long long rowb = (long long)(b*SEQ + l)*(3*DIM) + h*DQ + d;
  const float qv = __bfloat162float(qkv[rowb]) + __bfloat162float(qkv[rowb + PQKV3]);
  const float kv = __bfloat162float(qkv[rowb + DIM]) + __bfloat162float(qkv[rowb + DIM + PQKV3]);
  float sn, cs;
  sincosf(theta * (float)l, &sn, &cs);
  const long long dst = ((long long)(b*NH + h)*SEQ + l)*(2*DQ) + d;
  qrot[dst]      = __float2bfloat16(qv * cs);
  qrot[dst + DQ] = __float2bfloat16(qv * sn);
  krot[dst]      = __float2bfloat16(kv * cs);
  krot[dst + DQ] = __float2bfloat16(kv * sn);
  float sn2, cs2;
  sincosf(theta * (float)(l + 1), &sn2, &cs2);
  const float ad = dtab[h*(SEQ+1) + l + 1];
  qwb[dst]      = __float2bfloat16(qv * ad * cs2);
  qwb[dst + DQ] = __float2bfloat16(qv * ad * sn2);
}

// v (inside qkv pair) -> vt single [B,H,DQ,L], LDS-tiled transpose (coalesced)
__global__ void vt_kernel(const bf16* __restrict__ qkv, bf16* __restrict__ vt) {
  __shared__ float tile[64][65];
  const int t  = threadIdx.x;           // 256
  const int c  = t & 63, r4 = t >> 6;
  const int m0 = blockIdx.x * 64;
  const int d0 = blockIdx.y * 64;
  const int h  = blockIdx.z & (NH - 1);
  const int b  = blockIdx.z >> 3;
#pragma unroll
  for (int rr = 0; rr < 64; rr += 4) {
    const int m = m0 + rr + r4;
    const long long src = (long long)(b*SEQ + m)*(3*DIM) + 2*DIM + h*DQ + d0 + c;
    tile[rr + r4][c] = __bfloat162float(qkv[src]) + __bfloat162float(qkv[src + PQKV3]);
  }
  __syncthreads();
#pragma unroll
  for (int rr = 0; rr < 64; rr += 4) {
    const int d = rr + r4;
    vt[((long long)(b*NH + h)*DQ + d0 + d)*SEQ + m0 + c] = __float2bfloat16(tile[c][d]);
  }
}

// ret [B,H,L,DQ] f32 -> y pair [B,L,H*DQ] with silu
__global__ void siluret_kernel(const float* __restrict__ ret, bf16* __restrict__ y) {
  const int d = threadIdx.x, l = blockIdx.x, h = blockIdx.y, b = blockIdx.z;
  float r = ret[((long long)(b*NH + h)*SEQ + l)*DQ + d];
  float s = r / (1.f + __expf(-r));
  wpair(y, ((long long)(b*SEQ + l)*NH + h)*DQ + d, PY, s);
}

// ---------------------------------------------------------------------------
extern "C" void kernel_launch(void* const* d_in, const int* in_sizes, int n_in,
                              void* d_out, int out_size, void* d_ws, size_t ws_size,
                              hipStream_t stream) {
  const float* x      = (const float*)d_in[0];
  const float* tin_w  = (const float*)d_in[1];
  const float* tin_b  = (const float*)d_in[2];
  const float* tout_w = (const float*)d_in[3];
  const float* tout_b = (const float*)d_in[4];
  const float* wq_w   = (const float*)d_in[5];
  const float* wq_b   = (const float*)d_in[6];
  const float* wk_w   = (const float*)d_in[7];
  const float* wk_b   = (const float*)d_in[8];
  const float* wv_w   = (const float*)d_in[9];
  const float* wv_b   = (const float*)d_in[10];
  const float* wo_w   = (const float*)d_in[11];
  const float* wo_b   = (const float*)d_in[12];
  const float* f1_w   = (const float*)d_in[13];
  const float* f1_b   = (const float*)d_in[14];
  const float* f2_w   = (const float*)d_in[15];
  const float* f2_b   = (const float*)d_in[16];
  const float* phz_re = (const float*)d_in[17];
  const float* phz_im = (const float*)d_in[18];
  const float* amp    = (const float*)d_in[19];
  const float* lc_re  = (const float*)d_in[20];
  const float* lc_im  = (const float*)d_in[21];
  (void)in_sizes; (void)n_in; (void)out_size; (void)ws_size;

  char* w = (char*)d_ws;
  auto alloc = [&](size_t bytes) {
    char* p = w; w += (bytes + 255) & ~(size_t)255; return p;
  };
  auto palloc = [&](long long elems) {       // hi/lo pair, lo at +elems
    return (bf16*)alloc((size_t)elems * 2 * 2);
  };

  const long long WP = 3LL*DIM*DIM;
  float* h     = (float*)alloc((size_t)ROWS*DIM*4);
  float* ret   = (float*)alloc((size_t)BATCH*NH*SEQ*DQ*4);
  float* qkvbi = (float*)alloc((size_t)3*DIM*4);
  float* dtab  = (float*)alloc((size_t)NH*(SEQ+1)*4);
  bf16*  hb    = palloc(PQKV);
  bf16*  Wqkv  = palloc(WP);
  bf16*  Wol   = palloc((long long)DIM*DIM);
  bf16*  Wf1l  = palloc((long long)DH*DIM);
  bf16*  Wf2l  = (bf16*)alloc((size_t)DIM*DH*2);     // hi only (2-pass f2)
  bf16*  qkvb  = palloc(PQKV3);
  bf16*  lcc   = (bf16*)alloc((size_t)NH*DQ*2*DQ*2); // single plane
  bf16*  Wbig  = (bf16*)alloc((size_t)DIM*VOC*2);    // hi only (tin + 2-pass tout)
  bf16*  qrot  = (bf16*)alloc((size_t)PROT*2);       // single plane
  bf16*  krot  = (bf16*)alloc((size_t)PROT*2);       // single plane
  bf16*  qwb   = (bf16*)alloc((size_t)PROT*2);       // single plane
  bf16*  vtb   = (bf16*)alloc((size_t)PVT*2);        // single plane
  bf16*  Sb    = (bf16*)alloc((size_t)PS*2);         // single plane
  bf16*  mid   = palloc(PMID);
  // aliases (lifetimes disjoint):
  bf16*  xb = (bf16*)d_out;    // bf16 x in d_out; dead before tout writes
  bf16*  yb = qkvb;            // silu(ret) pair; qkvb dead after rotate/vt

  // grid: x = m-tiles (fastest -> B-panel reuse), y = n-tiles, z = batch*ksplit
  auto gemm = [&](int epi, int sa, int sb, const bf16* A, long long sA, long long pA, int lda,
                  const bf16* B, long long sB, long long pB, int ldb, int bmod,
                  void* C, long long sC, long long pC, int ldc,
                  const float* bias, int hmod, int M, int N, int K, int batch,
                  int ksplit, int causal) {
    dim3 g(M / BM, N / BN, batch * ksplit), blk(256);
    if (epi == 3 && !sa && !sb)      gemm_bt<3,0,0><<<g, blk, 0, stream>>>(A,sA,pA,lda,B,sB,pB,ldb,bmod,C,sC,pC,ldc,bias,hmod,M,N,K,ksplit,causal);
    else if (epi == 7)               gemm_bt<7,0,0><<<g, blk, 0, stream>>>(A,sA,pA,lda,B,sB,pB,ldb,bmod,C,sC,pC,ldc,bias,hmod,M,N,K,ksplit,causal);
    else if (epi == 0 && sa && !sb)  gemm_bt<0,1,0><<<g, blk, 0, stream>>>(A,sA,pA,lda,B,sB,pB,ldb,bmod,C,sC,pC,ldc,bias,hmod,M,N,K,ksplit,causal);
    else if (epi == 3 && sa && !sb)  gemm_bt<3,1,0><<<g, blk, 0, stream>>>(A,sA,pA,lda,B,sB,pB,ldb,bmod,C,sC,pC,ldc,bias,hmod,M,N,K,ksplit,causal);
    else if (epi == 3)               gemm_bt<3,1,1><<<g, blk, 0, stream>>>(A,sA,pA,lda,B,sB,pB,ldb,bmod,C,sC,pC,ldc,bias,hmod,M,N,K,ksplit,causal);
    else if (epi == 5)               gemm_bt<5,1,1><<<g, blk, 0, stream>>>(A,sA,pA,lda,B,sB,pB,ldb,bmod,C,sC,pC,ldc,bias,hmod,M,N,K,ksplit,causal);
    else if (epi == 6)               gemm_bt<6,1,1><<<g, blk, 0, stream>>>(A,sA,pA,lda,B,sB,pB,ldb,bmod,C,sC,pC,ldc,bias,hmod,M,N,K,ksplit,causal);
  };
  const int BIG = 1 << 30;

  // ---- input projection: h = x @ tin_w^T + tin_b  (split-K x10, atomic) ----
  tinprep_kernel<<<dim3((unsigned)((TIN_H4 + 255) / 256)), dim3(256), 0, stream>>>(
      x, xb, tin_w, Wbig, (float4*)h);
  gemm(3, 0, 0, xb, 0, 0, VOC, Wbig, 0, 0, VOC, BIG, h, 0, 0, DIM, tin_b, 1,
       ROWS, DIM, VOC, 1, 10, 0);

  for (int i = 0; i < DEPTH; ++i) {
    {
      long long tot4 = 12LL * ((long long)DIM*DIM >> 2);   // float4 count
      castw_kernel<<<dim3((unsigned)((tot4 + 255) / 256)), dim3(256), 0, stream>>>(
          wq_w + (size_t)i*DIM*DIM, wk_w + (size_t)i*DIM*DIM, wv_w + (size_t)i*DIM*DIM,
          wo_w + (size_t)i*DIM*DIM, f1_w + (size_t)i*DH*DIM, f2_w + (size_t)i*DIM*DH,
          Wqkv, Wol, Wf1l, Wf2l);
      misc_kernel<<<dim3((unsigned)((MISC_ZR + 255) / 256)), dim3(256), 0, stream>>>(
          lc_re + (size_t)i*NH*DQ*DQ, lc_im + (size_t)i*NH*DQ*DQ, lcc,
          wq_b + i*DIM, wk_b + i*DIM, wv_b + i*DIM, qkvbi,
          amp + i*NH, dtab, (float4*)ret);
    }

    // retention
    ln_kernel<<<ROWS, 256, 0, stream>>>(h, hb);
    // fused qkv = hb @ [Wq;Wk;Wv]^T + [bq;bk;bv]  (3-pass)
    gemm(5, 1, 1, hb, 0, PQKV, DIM, Wqkv, 0, WP, DIM, BIG,
         qkvb, 0, PQKV3, 3*DIM, qkvbi, 1, ROWS, 3*DIM, DIM, 1, 1, 0);
    rotate_kernel<<<dim3(SEQ, NH, BATCH), DQ, 0, stream>>>(
        qkvb, phz_re + i*NH*DQ, phz_im + i*NH*DQ, dtab, qrot, krot, qwb);
    vt_kernel<<<dim3(SEQ/64, DQ/64, BATCH*NH), 256, 0, stream>>>(qkvb, vtb);
    // S = (Qrot Krot^T) * decay-mask   (1-pass, causal tile-skip)
    gemm(7, 0, 0, qrot, (long long)SEQ*2*DQ, 0, 2*DQ,
         krot, (long long)SEQ*2*DQ, 0, 2*DQ, BIG,
         Sb, (long long)SEQ*SEQ, 0, SEQ, dtab, NH, SEQ, SEQ, 2*DQ, BATCH*NH, 1, 1);
    // ret = S @ V (1-pass, split-K x4, atomic, causal K-clamp) + cross (x2)
    gemm(3, 0, 0, Sb, (long long)SEQ*SEQ, 0, SEQ,
         vtb, (long long)DQ*SEQ, 0, SEQ, BIG,
         ret, (long long)SEQ*DQ, 0, DQ, nullptr, 1, SEQ, DQ, SEQ, BATCH*NH, 4, 2);
    gemm(3, 0, 0, qwb, (long long)SEQ*2*DQ, 0, 2*DQ,
         lcc, (long long)DQ*2*DQ, 0, 2*DQ, NH,
         ret, (long long)SEQ*DQ, 0, DQ, nullptr, 1, SEQ, DQ, 2*DQ, BATCH*NH, 2, 0);
    siluret_kernel<<<dim3(SEQ, NH, BATCH), DQ, 0, stream>>>(ret, yb);
    // h += y @ wo^T + wo_b   (3-pass, split-K x2)
    gemm(3, 1, 1, yb, 0, PY, DIM, Wol, 0, (long long)DIM*DIM, DIM, BIG,
         h, 0, 0, DIM, wo_b + i*DIM, 1, ROWS, DIM, DIM, 1, 2, 0);

    // FFN
    ln_kernel<<<ROWS, 256, 0, stream>>>(h, hb);
    gemm(6, 1, 1, hb, 0, PQKV, DIM, Wf1l, 0, (long long)DH*DIM, DIM, BIG,
         mid, 0, PMID, DH, f1_b + i*DH, 1, ROWS, DH, DIM, 1, 1, 0);
    // f2: 2-pass (A=mid pair, B=Wf2 hi only), split-K x4
    gemm(3, 1, 0, mid, 0, PMID, DH, Wf2l, 0, 0, DH, BIG,
         h, 0, 0, DIM, f2_b + i*DIM, 1, ROWS, DIM, DH, 1, 4, 0);
  }

  // ---- output projection: 2-pass (A=hb pair, B=tout_w hi only) ----
  tailprep_kernel<<<dim3((unsigned)((TAIL_W + 255) / 256)), dim3(256), 0, stream>>>(
      h, hb, tout_w, Wbig);
  gemm(0, 1, 0, hb, 0, PQKV, DIM, Wbig, 0, 0, DIM, BIG,
       (float*)d_out, 0, 0, VOC, tout_b, 1, ROWS, VOC, DIM, 1, 1, 0);
}

// Round 11
// 1740.403 us; speedup vs baseline: 1.2032x; 1.0423x over previous
//
#include <hip/hip_runtime.h>
#include <hip/hip_bf16.h>
#include <stdint.h>

#define DEPTH 4
#define DIM   1024
#define DH    4096
#define NH    8
#define DQ    128
#define VOC   32000
#define BATCH 2
#define SEQ   1024
#define ROWS  (BATCH*SEQ)   // 2048
#define CROSSK 256          // merged cross K-prefix in PV
#define LDS_X (CROSSK + SEQ)  // 1280: row length of SbX / vte

#define PQKV  ((long long)ROWS*DIM)
#define PQKV3 ((long long)ROWS*3*DIM)
#define PROT  ((long long)BATCH*NH*SEQ*2*DQ)
#define PMID  ((long long)ROWS*DH)
#define PY    ((long long)ROWS*DIM)

typedef __hip_bfloat16 bf16;
using f32x4  = __attribute__((ext_vector_type(4))) float;
using bf16x8 = __attribute__((ext_vector_type(8))) __bf16;

__device__ __forceinline__ unsigned short bcu(bf16 h) {
  return __builtin_bit_cast(unsigned short, h);
}

__device__ __forceinline__ void wpair(bf16* p, long long off, long long plane, float v) {
  bf16 hi = __float2bfloat16(v);
  p[off] = hi;
  p[off + plane] = __float2bfloat16(v - __bfloat162float(hi));
}

__device__ __forceinline__ void gload_lds16(const void* g, void* l) {
  __builtin_amdgcn_global_load_lds(
      (const __attribute__((address_space(1))) void*)g,
      (__attribute__((address_space(3))) void*)(uintptr_t)l,
      16, 0, 0);
}

// ---------------------------------------------------------------------------
// Batched GEMM: C[zb] = A[zb] (MxK rm) * B[zb%bmod]^T (NxK rm)
// Tile map: x = m-tiles (fastest -> B-panel L2/L3 reuse), y = n-tiles.
// blockIdx.z = zb*ksplit + kslice (Kc = K/ksplit columns).
// SA/SB: operand has a bf16 lo plane at +pA/+pB; passes = Ah*Bh [+Al*Bh] [+Ah*Bl].
// EPI 0: f32 C = acc+bias              3: f32 C += acc+bias (atomic if ksplit>1)
//     5: pair C = acc+bias             6: pair C = silu(acc+bias)
//     7: bf16 C = acc*decay, decay = dtab[(zb%hmod)*(SEQ+1) + (row-col)] (row>=col)
// causal: 1 = skip blocks fully above diagonal (S; skipped tiles never written)
//         2 = clamp K-loop to kend = tm+BM+CROSSK (PV+cross merged; skip if empty)
// bias added by slice 0 only.
// ---------------------------------------------------------------------------
#define BM 128
#define BN 128
#define BKK 64
#define PL 16384   // one LDS plane: 128 rows x 64 bf16

template<int EPI, int SA, int SB>
__global__ __launch_bounds__(256, (SA || SB) ? 2 : 4)
void gemm_bt(const bf16* __restrict__ A, long long sA, long long pA, int lda,
             const bf16* __restrict__ B, long long sB, long long pB, int ldb, int bmod,
             void* __restrict__ Cv, long long sC, long long pC, int ldc,
             const float* __restrict__ bias, int hmod,
             int M, int N, int K, int ksplit, int causal)
{
  __shared__ int4 sbuf[1024 * (2 + SA + SB)];
  char* Asb = (char*)sbuf;
  char* Bsb = Asb + PL * (1 + SA);

  const int tid  = threadIdx.x;
  const int lane = tid & 63;
  const int wave = tid >> 6;
  const int wr   = wave >> 1;
  const int wc   = wave & 1;
  const int z    = blockIdx.z;
  const int zb   = z / ksplit;
  const int ks   = z - zb * ksplit;
  const int Kc   = K / ksplit;
  const int k0   = ks * Kc;
  const int tm   = blockIdx.x * BM;
  const int tn   = blockIdx.y * BN;

  if (causal == 1 && tn >= tm + BM) return;      // fully-masked S tile
  int kend = k0 + Kc;
  if (causal == 2) {                              // merged cross+PV clamp
    kend = min(kend, tm + BM + CROSSK);
    if (kend <= k0) return;
  }

  const bf16* Ab = A + (long long)zb * sA;
  const bf16* Bb = B + (long long)(zb % bmod) * sB;

  f32x4 acc[4][4] = {};

  for (int kt = k0; kt < kend; kt += BKK) {
#pragma unroll
    for (int j = 0; j < 4; ++j) {
      int slot0 = j*256 + wave*64;          // wave-uniform LDS base
      int i = slot0 + lane;
      int row = i >> 3;
      int gc  = (i & 7) ^ (row & 7);        // inverse-swizzled global chunk
      long long ga = (long long)(tm + row) * lda + kt + gc*8;
      long long gb = (long long)(tn + row) * ldb + kt + gc*8;
      gload_lds16(Ab + ga, Asb + slot0*16);
      if (SA) gload_lds16(Ab + pA + ga, Asb + PL + slot0*16);
      gload_lds16(Bb + gb, Bsb + slot0*16);
      if (SB) gload_lds16(Bb + pB + gb, Bsb + PL + slot0*16);
    }
    __syncthreads();
#pragma unroll
    for (int kh = 0; kh < 2; ++kh) {
      const int cb = kh*4 + (lane >> 4);
      int4 avh[4], bvh[4], avl[4], bvl[4];
#pragma unroll
      for (int mi = 0; mi < 4; ++mi) {
        int m = wr*64 + mi*16 + (lane & 15);
        int off = m*128 + ((cb ^ (m & 7)) << 4);
        avh[mi] = *(const int4*)(Asb + off);
        if (SA) avl[mi] = *(const int4*)(Asb + PL + off);
      }
#pragma unroll
      for (int nj = 0; nj < 4; ++nj) {
        int n = wc*64 + nj*16 + (lane & 15);
        int off = n*128 + ((cb ^ (n & 7)) << 4);
        bvh[nj] = *(const int4*)(Bsb + off);
        if (SB) bvl[nj] = *(const int4*)(Bsb + PL + off);
      }
#pragma unroll
      for (int mi = 0; mi < 4; ++mi)
#pragma unroll
        for (int nj = 0; nj < 4; ++nj)
          acc[mi][nj] = __builtin_amdgcn_mfma_f32_16x16x32_bf16(
              __builtin_bit_cast(bf16x8, avh[mi]),
              __builtin_bit_cast(bf16x8, bvh[nj]), acc[mi][nj], 0, 0, 0);
      if (SA)
#pragma unroll
        for (int mi = 0; mi < 4; ++mi)
#pragma unroll
          for (int nj = 0; nj < 4; ++nj)
            acc[mi][nj] = __builtin_amdgcn_mfma_f32_16x16x32_bf16(
                __builtin_bit_cast(bf16x8, avl[mi]),
                __builtin_bit_cast(bf16x8, bvh[nj]), acc[mi][nj], 0, 0, 0);
      if (SB)
#pragma unroll
        for (int mi = 0; mi < 4; ++mi)
#pragma unroll
          for (int nj = 0; nj < 4; ++nj)
            acc[mi][nj] = __builtin_amdgcn_mfma_f32_16x16x32_bf16(
                __builtin_bit_cast(bf16x8, avh[mi]),
                __builtin_bit_cast(bf16x8, bvl[nj]), acc[mi][nj], 0, 0, 0);
    }
    __syncthreads();
  }

  const float* dtab = (EPI == 7) ? bias + (zb % hmod) * (SEQ + 1) : nullptr;
  const int col = lane & 15;
  const int rb  = (lane >> 4) << 2;
  float* Cf = (float*)Cv + (long long)zb * sC;
  bf16*  Ch = (bf16*) Cv + (long long)zb * sC;

#pragma unroll
  for (int mi = 0; mi < 4; ++mi)
#pragma unroll
    for (int nj = 0; nj < 4; ++nj) {
      long long gn = tn + wc*64 + nj*16 + col;
      float bv_ = (EPI != 7 && bias && ks == 0) ? bias[gn] : 0.f;
#pragma unroll
      for (int r = 0; r < 4; ++r) {
        long long gm = tm + wr*64 + mi*16 + rb + r;
        float v = acc[mi][nj][r] + bv_;
        long long off = gm * (long long)ldc + gn;
        if (EPI == 0)      Cf[off] = v;
        else if (EPI == 3) { if (ksplit > 1) atomicAdd(&Cf[off], v); else Cf[off] += v; }
        else if (EPI == 5) wpair(Ch, off, pC, v);
        else if (EPI == 6) wpair(Ch, off, pC, v / (1.f + __expf(-v)));
        else {
          long long dlt = gm - gn;
          float dcy = (dlt >= 0) ? dtab[dlt] : 0.f;
          Ch[off] = __float2bfloat16(acc[mi][nj][r] * dcy);
        }
      }
    }
}

// ---------------------------------------------------------------------------
// Fused per-layer prep (ONE launch):
//  part 1 (float4-vectorized weight cast): Wqkv pair (3M), Wol pair (1M),
//          Wf1 pair (4M), Wf2 single (4M)  -> 12*S4 float4 units
//  part 2 (misc, scalar units appended):
//   lcc -> vte cols [0,CROSSK) replicated per batch; theta table;
//   qkv bias concat; decay table; zero ret.
#define MC_LC (NH*DQ*DQ)                    // 131072
#define MC_TH (MC_LC + NH*DQ)               // +1024
#define MC_B3 (MC_TH + 3*DIM)               // +3072
#define MC_DC (MC_B3 + NH*(SEQ+1))          // +8200
#define MC_ZR (MC_DC + (BATCH*NH*SEQ*DQ)/4) // +524288
__global__ void prep_kernel(const float* __restrict__ wq, const float* __restrict__ wk,
                            const float* __restrict__ wv, const float* __restrict__ wo,
                            const float* __restrict__ f1, const float* __restrict__ f2,
                            bf16* __restrict__ Wqkv, bf16* __restrict__ Wol,
                            bf16* __restrict__ Wf1, bf16* __restrict__ Wf2,
                            const float* __restrict__ lcr, const float* __restrict__ lci,
                            bf16* __restrict__ vte,
                            const float* __restrict__ pre, const float* __restrict__ pim,
                            float* __restrict__ theta,
                            const float* __restrict__ bq, const float* __restrict__ bk,
                            const float* __restrict__ bv, float* __restrict__ qkvbi,
                            const float* __restrict__ amp, float* __restrict__ dtab,
                            float4* __restrict__ retz) {
  const long long S1 = (long long)DIM*DIM;   // 1M elems
  const long long S4 = S1 >> 2;
  const long long WPq = 3*S1;
  const long long CW4 = 12*S4;
  long long i = (long long)blockIdx.x * blockDim.x + threadIdx.x;
  if (i < CW4) {
    const float* src; bf16 *hi, *lo; long long j4;
    if (i < 3*S4) {
      int t = (int)(i / S4);
      src = (t == 0) ? wq : (t == 1) ? wk : wv;
      j4 = i - (long long)t * S4;
      hi = Wqkv + (long long)t * S1; lo = hi + WPq;
    } else if (i < 4*S4)  { src = wo; j4 = i - 3*S4; hi = Wol; lo = Wol + S1; }
    else if (i < 8*S4)    { src = f1; j4 = i - 4*S4; hi = Wf1; lo = Wf1 + 4*S1; }
    else                  { src = f2; j4 = i - 8*S4; hi = Wf2; lo = nullptr; }
    float4 v = ((const float4*)src)[j4];
    bf16 h0 = __float2bfloat16(v.x), h1 = __float2bfloat16(v.y);
    bf16 h2 = __float2bfloat16(v.z), h3 = __float2bfloat16(v.w);
    ((ushort4*)hi)[j4] = ushort4{bcu(h0), bcu(h1), bcu(h2), bcu(h3)};
    if (lo) {
      bf16 l0 = __float2bfloat16(v.x - __bfloat162float(h0));
      bf16 l1 = __float2bfloat16(v.y - __bfloat162float(h1));
      bf16 l2 = __float2bfloat16(v.z - __bfloat162float(h2));
      bf16 l3 = __float2bfloat16(v.w - __bfloat162float(h3));
      ((ushort4*)lo)[j4] = ushort4{bcu(l0), bcu(l1), bcu(l2), bcu(l3)};
    }
    return;
  }
  long long j = i - CW4;
  if (j < MC_LC) {
    int d = (int)(j & 127), e = (int)((j >> 7) & 127), h = (int)(j >> 14);
    float vr = lcr[((long long)h*DQ + d)*DQ + e];
    float vi = lci[((long long)h*DQ + d)*DQ + e];
    bf16 br = __float2bfloat16(vr), bi = __float2bfloat16(-vi);
#pragma unroll
    for (int b = 0; b < BATCH; ++b) {
      long long base = ((long long)(b*NH + h)*DQ + e) * LDS_X;
      vte[base + d]      = br;
      vte[base + DQ + d] = bi;
    }
  } else if (j < MC_TH) {
    int t = (int)(j - MC_LC);
    theta[t] = atan2f(pim[t], pre[t]);
  } else if (j < MC_B3) {
    int t = (int)(j - MC_TH);
    qkvbi[t] = (t < DIM) ? bq[t] : (t < 2*DIM) ? bk[t - DIM] : bv[t - 2*DIM];
  } else if (j < MC_DC) {
    int t = (int)(j - MC_B3);
    int h = t / (SEQ+1), n = t % (SEQ+1);
    float a = 1.f / (1.f + __expf(-amp[h]));
    dtab[t] = powf(a, (float)n);
  } else if (j < MC_ZR) {
    retz[j - MC_DC] = float4{0.f, 0.f, 0.f, 0.f};
  }
}

// tin prep: cast x (4-wide), cast tin_w (4-wide), zero h (float4), one launch.
#define TIN_X4 ((long long)ROWS*VOC/4)
#define TIN_W4 (TIN_X4 + (long long)DIM*VOC/4)
#define TIN_H4 (TIN_W4 + (long long)ROWS*DIM/4)
__global__ void tinprep_kernel(const float* __restrict__ x, bf16* __restrict__ xb,
                               const float* __restrict__ tw, bf16* __restrict__ twb,
                               float4* __restrict__ hz) {
  long long i = (long long)blockIdx.x * blockDim.x + threadIdx.x;
  const float* src; bf16* dst; long long j;
  if (i < TIN_X4)      { src = x;  dst = xb;  j = i; }
  else if (i < TIN_W4) { src = tw; dst = twb; j = i - TIN_X4; }
  else if (i < TIN_H4) { hz[i - TIN_W4] = float4{0.f,0.f,0.f,0.f}; return; }
  else return;
  float4 v = ((const float4*)src)[j];
  ushort4 o{bcu(__float2bfloat16(v.x)), bcu(__float2bfloat16(v.y)),
            bcu(__float2bfloat16(v.z)), bcu(__float2bfloat16(v.w))};
  ((ushort4*)dst)[j] = o;
}

// tail prep: pair-cast h -> hb + cast tout_w (4-wide), one launch.
#define TAIL_H (PQKV)
#define TAIL_W (TAIL_H + (long long)VOC*DIM/4)
__global__ void tailprep_kernel(const float* __restrict__ h, bf16* __restrict__ hb,
                                const float* __restrict__ tw, bf16* __restrict__ twb) {
  long long i = (long long)blockIdx.x * blockDim.x + threadIdx.x;
  if (i < TAIL_H) {
    float v = h[i];
    bf16 hi = __float2bfloat16(v);
    hb[i] = hi;
    hb[i + PQKV] = __float2bfloat16(v - __bfloat162float(hi));
  } else if (i < TAIL_W) {
    long long j = i - TAIL_H;
    float4 v = ((const float4*)tw)[j];
    ushort4 o{bcu(__float2bfloat16(v.x)), bcu(__float2bfloat16(v.y)),
              bcu(__float2bfloat16(v.z)), bcu(__float2bfloat16(v.w))};
    ((ushort4*)twb)[j] = o;
  }
}

__global__ void ln_kernel(const float* __restrict__ in, bf16* __restrict__ out) {
  const int row = blockIdx.x;
  const int tid = threadIdx.x;          // 256
  const float4 v = ((const float4*)(in + (size_t)row*DIM))[tid];
  float s  = v.x + v.y + v.z + v.w;
  float s2 = v.x*v.x + v.y*v.y + v.z*v.z + v.w*v.w;
#pragma unroll
  for (int o = 32; o > 0; o >>= 1) { s += __shfl_xor(s, o); s2 += __shfl_xor(s2, o); }
  __shared__ float red[8];
  const int wv = tid >> 6;
  if ((tid & 63) == 0) { red[wv] = s; red[4 + wv] = s2; }
  __syncthreads();
  s  = red[0] + red[1] + red[2] + red[3];
  s2 = red[4] + red[5] + red[6] + red[7];
  const float mean = s * (1.f / DIM);
  const float var  = s2 * (1.f / DIM) - mean * mean;
  const float inv  = rsqrtf(var + 1e-5f);
  float e0 = (v.x - mean) * inv, e1 = (v.y - mean) * inv;
  float e2 = (v.z - mean) * inv, e3 = (v.w - mean) * inv;
  bf16 h0 = __float2bfloat16(e0), h1 = __float2bfloat16(e1);
  bf16 h2 = __float2bfloat16(e2), h3 = __float2bfloat16(e3);
  bf16 l0 = __float2bfloat16(e0 - __bfloat162float(h0));
  bf16 l1 = __float2bfloat16(e1 - __bfloat162float(h1));
  bf16 l2 = __float2bfloat16(e2 - __bfloat162float(h2));
  bf16 l3 = __float2bfloat16(e3 - __bfloat162float(h3));
  ((ushort4*)(out + (size_t)row*DIM))[tid]        = ushort4{bcu(h0), bcu(h1), bcu(h2), bcu(h3)};
  ((ushort4*)(out + PQKV + (size_t)row*DIM))[tid] = ushort4{bcu(l0), bcu(l1), bcu(l2), bcu(l3)};
}

// qkv pair [B,L,3*DIM] -> qrot/krot [B,H,L,2*DQ]; qwb -> SbX cols [0,CROSSK)
__global__ void rotate_kernel(const bf16* __restrict__ qkv,
                              const float* __restrict__ theta_t,
                              const float* __restrict__ dtab,
                              bf16* __restrict__ qrot, bf16* __restrict__ krot,
                              bf16* __restrict__ SbX) {
  const int d = threadIdx.x, l = blockIdx.x, h = blockIdx.y, b = blockIdx.z;
  const float theta = theta_t[h*DQ + d];
  const long long rowb = (long long)(b*SEQ + l)*(3*DIM) + h*DQ + d;
  const float qv = __bfloat162float(qkv[rowb]) + __bfloat162float(qkv[rowb + PQKV3]);
  const float kv = __bfloat162float(qkv[rowb + DIM]) + __bfloat162float(qkv[rowb + DIM + PQKV3]);
  float sn, cs;
  sincosf(theta * (float)l, &sn, &cs);
  const long long dst = ((long long)(b*NH + h)*SEQ + l)*(2*DQ) + d;
  qrot[dst]      = __float2bfloat16(qv * cs);
  qrot[dst + DQ] = __float2bfloat16(qv * sn);
  krot[dst]      = __float2bfloat16(kv * cs);
  krot[dst + DQ] = __float2bfloat16(kv * sn);
  float sn2, cs2;
  sincosf(theta * (float)(l + 1), &sn2, &cs2);
  const float ad = dtab[h*(SEQ+1) + l + 1];
  const long long qw = ((long long)(b*NH + h)*SEQ + l)*LDS_X + d;
  SbX[qw]      = __float2bfloat16(qv * ad * cs2);
  SbX[qw + DQ] = __float2bfloat16(qv * ad * sn2);
}

// v (inside qkv pair) -> vte cols [CROSSK, CROSSK+SEQ), LDS-tiled transpose
__global__ void vt_kernel(const bf16* __restrict__ qkv, bf16* __restrict__ vte) {
  __shared__ float tile[64][65];
  const int t  = threadIdx.x;           // 256
  const int c  = t & 63, r4 = t >> 6;
  const int m0 = blockIdx.x * 64;
  const int d0 = blockIdx.y * 64;
  const int h  = blockIdx.z & (NH - 1);
  const int b  = blockIdx.z >> 3;
#pragma unroll
  for (int rr = 0; rr < 64; rr += 4) {
    const int m = m0 + rr + r4;
    const long long src = (long long)(b*SEQ + m)*(3*DIM) + 2*DIM + h*DQ + d0 + c;
    tile[rr + r4][c] = __bfloat162float(qkv[src]) + __bfloat162float(qkv[src + PQKV3]);
  }
  __syncthreads();
#pragma unroll
  for (int rr = 0; rr < 64; rr += 4) {
    const int d = rr + r4;
    vte[((long long)(b*NH + h)*DQ + d0 + d)*LDS_X + CROSSK + m0 + c] =
        __float2bfloat16(tile[c][d]);
  }
}

// ret [B,H,L,DQ] f32 -> y pair [B,L,H*DQ] with silu
__global__ void siluret_kernel(const float* __restrict__ ret, bf16* __restrict__ y) {
  const int d = threadIdx.x, l = blockIdx.x, h = blockIdx.y, b = blockIdx.z;
  float r = ret[((long long)(b*NH + h)*SEQ + l)*DQ + d];
  float s = r / (1.f + __expf(-r));
  wpair(y, ((long long)(b*SEQ + l)*NH + h)*DQ + d, PY, s);
}

// ---------------------------------------------------------------------------
extern "C" void kernel_launch(void* const* d_in, const int* in_sizes, int n_in,
                              void* d_out, int out_size, void* d_ws, size_t ws_size,
                              hipStream_t stream) {
  const float* x      = (const float*)d_in[0];
  const float* tin_w  = (const float*)d_in[1];
  const float* tin_b  = (const float*)d_in[2];
  const float* tout_w = (const float*)d_in[3];
  const float* tout_b = (const float*)d_in[4];
  const float* wq_w   = (const float*)d_in[5];
  const float* wq_b   = (const float*)d_in[6];
  const float* wk_w   = (const float*)d_in[7];
  const float* wk_b   = (const float*)d_in[8];
  const float* wv_w   = (const float*)d_in[9];
  const float* wv_b   = (const float*)d_in[10];
  const float* wo_w   = (const float*)d_in[11];
  const float* wo_b   = (const float*)d_in[12];
  const float* f1_w   = (const float*)d_in[13];
  const float* f1_b   = (const float*)d_in[14];
  const float* f2_w   = (const float*)d_in[15];
  const float* f2_b   = (const float*)d_in[16];
  const float* phz_re = (const float*)d_in[17];
  const float* phz_im = (const float*)d_in[18];
  const float* amp    = (const float*)d_in[19];
  const float* lc_re  = (const float*)d_in[20];
  const float* lc_im  = (const float*)d_in[21];
  (void)in_sizes; (void)n_in; (void)out_size; (void)ws_size;

  char* w = (char*)d_ws;
  auto alloc = [&](size_t bytes) {
    char* p = w; w += (bytes + 255) & ~(size_t)255; return p;
  };
  auto palloc = [&](long long elems) {       // hi/lo pair, lo at +elems
    return (bf16*)alloc((size_t)elems * 2 * 2);
  };

  const long long WP = 3LL*DIM*DIM;
  float* h     = (float*)alloc((size_t)ROWS*DIM*4);
  float* ret   = (float*)alloc((size_t)BATCH*NH*SEQ*DQ*4);
  float* qkvbi = (float*)alloc((size_t)3*DIM*4);
  float* dtab  = (float*)alloc((size_t)NH*(SEQ+1)*4);
  float* theta = (float*)alloc((size_t)NH*DQ*4);
  bf16*  hb    = palloc(PQKV);
  bf16*  Wqkv  = palloc(WP);
  bf16*  Wol   = palloc((long long)DIM*DIM);
  bf16*  Wf1l  = palloc((long long)DH*DIM);
  bf16*  Wf2l  = (bf16*)alloc((size_t)DIM*DH*2);     // hi only (2-pass f2)
  bf16*  qkvb  = palloc(PQKV3);
  bf16*  Wbig  = (bf16*)alloc((size_t)DIM*VOC*2);    // hi only (tin + 2-pass tout)
  bf16*  qrot  = (bf16*)alloc((size_t)PROT*2);       // single plane
  bf16*  krot  = (bf16*)alloc((size_t)PROT*2);       // single plane
  bf16*  SbX   = (bf16*)alloc((size_t)BATCH*NH*SEQ*LDS_X*2);  // [qwb | S]
  bf16*  vte   = (bf16*)alloc((size_t)BATCH*NH*DQ*LDS_X*2);   // [lcc | V^T]
  bf16*  mid   = palloc(PMID);
  // aliases (lifetimes disjoint):
  bf16*  xb = (bf16*)d_out;    // bf16 x in d_out; dead before tout writes
  bf16*  yb = qkvb;            // silu(ret) pair; qkvb dead after rotate/vt

  // grid: x = m-tiles (fastest -> B-panel reuse), y = n-tiles, z = batch*ksplit
  auto gemm = [&](int epi, int sa, int sb, const bf16* A, long long sA, long long pA, int lda,
                  const bf16* B, long long sB, long long pB, int ldb, int bmod,
                  void* C, long long sC, long long pC, int ldc,
                  const float* bias, int hmod, int M, int N, int K, int batch,
                  int ksplit, int causal) {
    dim3 g(M / BM, N / BN, batch * ksplit), blk(256);
    if (epi == 3 && !sa && !sb)      gemm_bt<3,0,0><<<g, blk, 0, stream>>>(A,sA,pA,lda,B,sB,pB,ldb,bmod,C,sC,pC,ldc,bias,hmod,M,N,K,ksplit,causal);
    else if (epi == 7)               gemm_bt<7,0,0><<<g, blk, 0, stream>>>(A,sA,pA,lda,B,sB,pB,ldb,bmod,C,sC,pC,ldc,bias,hmod,M,N,K,ksplit,causal);
    else if (epi == 0 && sa && !sb)  gemm_bt<0,1,0><<<g, blk, 0, stream>>>(A,sA,pA,lda,B,sB,pB,ldb,bmod,C,sC,pC,ldc,bias,hmod,M,N,K,ksplit,causal);
    else if (epi == 3 && sa && !sb)  gemm_bt<3,1,0><<<g, blk, 0, stream>>>(A,sA,pA,lda,B,sB,pB,ldb,bmod,C,sC,pC,ldc,bias,hmod,M,N,K,ksplit,causal);
    else if (epi == 3)               gemm_bt<3,1,1><<<g, blk, 0, stream>>>(A,sA,pA,lda,B,sB,pB,ldb,bmod,C,sC,pC,ldc,bias,hmod,M,N,K,ksplit,causal);
    else if (epi == 5)               gemm_bt<5,1,1><<<g, blk, 0, stream>>>(A,sA,pA,lda,B,sB,pB,ldb,bmod,C,sC,pC,ldc,bias,hmod,M,N,K,ksplit,causal);
    else if (epi == 6)               gemm_bt<6,1,1><<<g, blk, 0, stream>>>(A,sA,pA,lda,B,sB,pB,ldb,bmod,C,sC,pC,ldc,bias,hmod,M,N,K,ksplit,causal);
  };
  const int BIG = 1 << 30;

  // ---- input projection: h = x @ tin_w^T + tin_b  (split-K x10, atomic) ----
  tinprep_kernel<<<dim3((unsigned)((TIN_H4 + 255) / 256)), dim3(256), 0, stream>>>(
      x, xb, tin_w, Wbig, (float4*)h);
  gemm(3, 0, 0, xb, 0, 0, VOC, Wbig, 0, 0, VOC, BIG, h, 0, 0, DIM, tin_b, 1,
       ROWS, DIM, VOC, 1, 10, 0);

  for (int i = 0; i < DEPTH; ++i) {
    {
      long long tot = 12LL*((long long)DIM*DIM >> 2) + MC_ZR;
      prep_kernel<<<dim3((unsigned)((tot + 255) / 256)), dim3(256), 0, stream>>>(
          wq_w + (size_t)i*DIM*DIM, wk_w + (size_t)i*DIM*DIM, wv_w + (size_t)i*DIM*DIM,
          wo_w + (size_t)i*DIM*DIM, f1_w + (size_t)i*DH*DIM, f2_w + (size_t)i*DIM*DH,
          Wqkv, Wol, Wf1l, Wf2l,
          lc_re + (size_t)i*NH*DQ*DQ, lc_im + (size_t)i*NH*DQ*DQ, vte,
          phz_re + i*NH*DQ, phz_im + i*NH*DQ, theta,
          wq_b + i*DIM, wk_b + i*DIM, wv_b + i*DIM, qkvbi,
          amp + i*NH, dtab, (float4*)ret);
    }

    // retention
    ln_kernel<<<ROWS, 256, 0, stream>>>(h, hb);
    // fused qkv = hb @ [Wq;Wk;Wv]^T + [bq;bk;bv]  (3-pass)
    gemm(5, 1, 1, hb, 0, PQKV, DIM, Wqkv, 0, WP, DIM, BIG,
         qkvb, 0, PQKV3, 3*DIM, qkvbi, 1, ROWS, 3*DIM, DIM, 1, 1, 0);
    rotate_kernel<<<dim3(SEQ, NH, BATCH), DQ, 0, stream>>>(
        qkvb, theta, dtab, qrot, krot, SbX);
    vt_kernel<<<dim3(SEQ/64, DQ/64, BATCH*NH), 256, 0, stream>>>(qkvb, vte);
    // S = (Qrot Krot^T) * decay-mask -> SbX cols [CROSSK,..) (causal tile-skip)
    gemm(7, 0, 0, qrot, (long long)SEQ*2*DQ, 0, 2*DQ,
         krot, (long long)SEQ*2*DQ, 0, 2*DQ, BIG,
         SbX + CROSSK, (long long)SEQ*LDS_X, 0, LDS_X, dtab, NH,
         SEQ, SEQ, 2*DQ, BATCH*NH, 1, 1);
    // ret = [qwb|S] @ [lcc|V^T]^T  (merged cross+PV, split-K x4, causal clamp)
    gemm(3, 0, 0, SbX, (long long)SEQ*LDS_X, 0, LDS_X,
         vte, (long long)DQ*LDS_X, 0, LDS_X, BIG,
         ret, (long long)SEQ*DQ, 0, DQ, nullptr, 1, SEQ, DQ, LDS_X, BATCH*NH, 4, 2);
    siluret_kernel<<<dim3(SEQ, NH, BATCH), DQ, 0, stream>>>(ret, yb);
    // h += y @ wo^T + wo_b   (3-pass, split-K x2)
    gemm(3, 1, 1, yb, 0, PY, DIM, Wol, 0, (long long)DIM*DIM, DIM, BIG,
         h, 0, 0, DIM, wo_b + i*DIM, 1, ROWS, DIM, DIM, 1, 2, 0);

    // FFN
    ln_kernel<<<ROWS, 256, 0, stream>>>(h, hb);
    gemm(6, 1, 1, hb, 0, PQKV, DIM, Wf1l, 0, (long long)DH*DIM, DIM, BIG,
         mid, 0, PMID, DH, f1_b + i*DH, 1, ROWS, DH, DIM, 1, 1, 0);
    // f2: 2-pass (A=mid pair, B=Wf2 hi only), split-K x4
    gemm(3, 1, 0, mid, 0, PMID, DH, Wf2l, 0, 0, DH, BIG,
         h, 0, 0, DIM, f2_b + i*DIM, 1, ROWS, DIM, DH, 1, 4, 0);
  }

  // ---- output projection: 2-pass (A=hb pair, B=tout_w hi only) ----
  tailprep_kernel<<<dim3((unsigned)((TAIL_W + 255) / 256)), dim3(256), 0, stream>>>(
      h, hb, tout_w, Wbig);
  gemm(0, 1, 0, hb, 0, PQKV, DIM, Wbig, 0, 0, DIM, BIG,
       (float*)d_out, 0, 0, VOC, tout_b, 1, ROWS, VOC, DIM, 1, 1, 0);
}